// Round 8
// baseline (162.553 us; speedup 1.0000x reference)
//
#include <hip/hip_runtime.h>

// Problem constants
constexpr int BN_  = 16;                 // batch
constexpr int SN_  = 577;                // seq
constexpr int SP_  = 640;                // padded seq (multiple of 64)
constexpr int DN_  = 768;                // model dim
constexpr int HN_  = 12;                 // heads
constexpr int HD_  = 64;                 // head dim
constexpr int NB_  = 50;                 // rpe buckets
constexpr int MR_  = BN_ * SN_;          // 9232 rows of x
constexpr int MRP_ = 73 * 128;           // 9344 padded rows
constexpr int NQ_  = 3 * DN_;            // 2304 qkv cols
constexpr int BHS_ = BN_ * HN_ * SN_;    // 110784 (b,h,i) rows
constexpr int SHD_ = SN_ * HD_;          // 36928

typedef __attribute__((ext_vector_type(8))) short short8;
typedef __attribute__((ext_vector_type(4))) float f32x4;

__device__ __forceinline__ short f2bf(float f) {
  union { float f; unsigned u; } v; v.f = f;
  unsigned r = (v.u + 0x7fffu + ((v.u >> 16) & 1u)) >> 16;
  return (short)r;
}

// raw v_exp_f32: D = 2^S0 (handles -3e38 -> 0)
__device__ __forceinline__ float ex2(float x) {
  float r; asm("v_exp_f32 %0, %1" : "=v"(r) : "v"(x)); return r;
}

// v_cvt_pk_bf16_f32: dst = {lo16=bf16(a), hi16=bf16(b)}
__device__ __forceinline__ unsigned cvtpk(float a, float b) {
  unsigned r; asm("v_cvt_pk_bf16_f32 %0, %1, %2" : "=v"(r) : "v"(a), "v"(b));
  return r;
}

__device__ __forceinline__ float bf2f(unsigned short u) {
  union { unsigned u; float f; } v; v.u = ((unsigned)u) << 16; return v.f;
}

// ---------------------------------------------------------------------------
// Kernel 0: f32 -> bf16 convert (pads dst beyond n_src with zeros)
// ---------------------------------------------------------------------------
__launch_bounds__(256)
__global__ void cvt_k(const float* __restrict__ src, short* __restrict__ dst,
                      int n_src, int n_dst) {
  const int i = (blockIdx.x * 256 + threadIdx.x) * 8;
  if (i >= n_dst) return;
  union { short8 v; short u[8]; } pk;
  if (i < n_src) {
    const float4 a = *(const float4*)(src + i);
    const float4 b = *(const float4*)(src + i + 4);
    pk.u[0] = f2bf(a.x); pk.u[1] = f2bf(a.y); pk.u[2] = f2bf(a.z); pk.u[3] = f2bf(a.w);
    pk.u[4] = f2bf(b.x); pk.u[5] = f2bf(b.y); pk.u[6] = f2bf(b.z); pk.u[7] = f2bf(b.w);
  } else {
#pragma unroll
    for (int j = 0; j < 8; ++j) pk.u[j] = 0;
  }
  *(short8*)(dst + i) = pk.v;
}

// ---------------------------------------------------------------------------
// Kernel 0b: rp_bucket int32 [577][577] -> u8 [577][640] (pad j with 0)
// ---------------------------------------------------------------------------
__launch_bounds__(256)
__global__ void rpb8_k(const int* __restrict__ rpb, unsigned char* __restrict__ rpbu8) {
  const int tid = blockIdx.x * 256 + threadIdx.x;
  if (tid >= SN_ * 160) return;
  const int i = tid / 160, c4 = tid - i * 160;
  const int j = c4 * 4;
  uchar4 o;
  o.x = (j     < SN_) ? (unsigned char)rpb[i * SN_ + j    ] : 0;
  o.y = (j + 1 < SN_) ? (unsigned char)rpb[i * SN_ + j + 1] : 0;
  o.z = (j + 2 < SN_) ? (unsigned char)rpb[i * SN_ + j + 2] : 0;
  o.w = (j + 3 < SN_) ? (unsigned char)rpb[i * SN_ + j + 3] : 0;
  *(uchar4*)(rpbu8 + (size_t)i * 640 + j) = o;
}

// ---------------------------------------------------------------------------
// Kernel 1: qkv = x @ w^T in bf16 MFMA (unchanged from R6).
// ---------------------------------------------------------------------------
__launch_bounds__(256)
__global__ void qkv_mfma_k(const short* __restrict__ xb, const short* __restrict__ wb,
                           short* __restrict__ Qbf, short* __restrict__ Ksw,
                           short* __restrict__ Vbf) {
  __shared__ short At[128 * 64];
  __shared__ short Bt[128 * 64];
  const int t = threadIdx.x;
  const int w = t >> 6, lane = t & 63, g = lane >> 4, ln = lane & 15;
  const int wm = w >> 1, wn = w & 1;
  const int m0 = blockIdx.y * 128, n0 = blockIdx.x * 128;

  const int sr = t >> 1, su = (t & 1) * 4;
  const short* ga = xb + (size_t)(m0 + sr) * DN_ + su * 8;
  const short* gb = wb + (size_t)(n0 + sr) * DN_ + su * 8;
  short* la = At + sr * 64;
  short* lb = Bt + sr * 64;
  const int swr = sr & 7;

  f32x4 acc[4][4];
#pragma unroll
  for (int mt = 0; mt < 4; ++mt)
#pragma unroll
    for (int nt = 0; nt < 4; ++nt) acc[mt][nt] = (f32x4){0.f, 0.f, 0.f, 0.f};

  short8 ra[4], rb[4];
#pragma unroll
  for (int u = 0; u < 4; ++u) {
    ra[u] = *(const short8*)(ga + u * 8);
    rb[u] = *(const short8*)(gb + u * 8);
  }

  for (int k0 = 0; k0 < DN_; k0 += 64) {
    __syncthreads();  // prior iteration's frag reads complete
#pragma unroll
    for (int u = 0; u < 4; ++u) {
      *(short8*)(la + (((su + u) ^ swr) * 8)) = ra[u];
      *(short8*)(lb + (((su + u) ^ swr) * 8)) = rb[u];
    }
    __syncthreads();  // tiles visible
    if (k0 + 64 < DN_) {
#pragma unroll
      for (int u = 0; u < 4; ++u) {
        ra[u] = *(const short8*)(ga + k0 + 64 + u * 8);
        rb[u] = *(const short8*)(gb + k0 + 64 + u * 8);
      }
    }
#pragma unroll
    for (int kc = 0; kc < 2; ++kc) {
      short8 af[4], bf[4];
#pragma unroll
      for (int mt = 0; mt < 4; ++mt) {
        const int row = wm * 64 + mt * 16 + ln;
        const int u = (kc * 4 + g) ^ (row & 7);
        af[mt] = *(const short8*)&At[row * 64 + u * 8];
      }
#pragma unroll
      for (int nt = 0; nt < 4; ++nt) {
        const int row = wn * 64 + nt * 16 + ln;
        const int u = (kc * 4 + g) ^ (row & 7);
        bf[nt] = *(const short8*)&Bt[row * 64 + u * 8];
      }
#pragma unroll
      for (int mt = 0; mt < 4; ++mt)
#pragma unroll
        for (int nt = 0; nt < 4; ++nt)
          acc[mt][nt] = __builtin_amdgcn_mfma_f32_16x16x32_bf16(af[mt], bf[nt], acc[mt][nt], 0, 0, 0);
    }
  }

  const int nw0  = n0 + wn * 64;
  const int secg = nw0 / DN_;               // uniform per wave
  const int cbw  = nw0 - secg * DN_;
  const float QSC = 0.18033688011112042f;   // log2(e) / 8
#pragma unroll
  for (int mt = 0; mt < 4; ++mt) {
#pragma unroll
    for (int r = 0; r < 4; ++r) {
      const int gm = m0 + wm * 64 + mt * 16 + 4 * g + r;
      if (gm >= MR_) continue;
      const int bb = gm / SN_;
      const int ss = gm - bb * SN_;
      const int pb = ss * DN_ + cbw;
#pragma unroll
      for (int nt = 0; nt < 4; ++nt) {
        const int p   = pb + nt * 16 + ln;
        const int hh  = p / SHD_;
        const int rem = p - hh * SHD_;
        const int ii  = rem >> 6;
        const int dd  = rem & 63;
        const size_t ro = (size_t)(bb * HN_ + hh);
        const float v = acc[mt][nt][r];
        if (secg == 0) {
          Qbf[(ro * SN_ + ii) * 64 + dd] = f2bf(v * QSC);
        } else if (secg == 1) {
          Ksw[(ro * SP_ + ii) * 64 + (dd ^ ((ii & 7) << 3))] = f2bf(v);
        } else {
          Vbf[(ro * SP_ + ii) * 64 + dd] = f2bf(v);
        }
      }
    }
  }
}

// ---------------------------------------------------------------------------
// Kernel 2: transpose V per (bh): Vbf[j][d] -> Vtsw[d][j], bf16, swizzled
// (short col index ^ ((d&7)<<3)); pad cols j>=577 zeroed.
// ---------------------------------------------------------------------------
__launch_bounds__(256)
__global__ void vtr_k(const short* __restrict__ Vbf, short* __restrict__ Vtsw) {
  __shared__ short T[64][72];
  const int t = threadIdx.x;
  const int jt = blockIdx.x, bh = blockIdx.y;
  const int j0 = jt * 64;
  {
    const int r = t >> 2, c0 = (t & 3) * 16;
    const short* src = Vbf + ((size_t)bh * SP_ + j0 + r) * 64 + c0;
    *(short8*)&T[r][c0]     = *(const short8*)(src);
    *(short8*)&T[r][c0 + 8] = *(const short8*)(src + 8);
  }
  __syncthreads();
  const int d = t >> 2;
  short* dst = Vtsw + ((size_t)bh * 64 + d) * SP_;
  const int sw = (d & 7) << 3;
#pragma unroll
  for (int e = 0; e < 4; ++e) {
    const int jl = (t & 3) * 16 + e * 4;
    const int jg = j0 + jl;
    short4 v;
    v.x = (jg + 0 < SN_) ? T[jl + 0][d] : (short)0;
    v.y = (jg + 1 < SN_) ? T[jl + 1][d] : (short)0;
    v.z = (jg + 2 < SN_) ? T[jl + 2][d] : (short)0;
    v.w = (jg + 3 < SN_) ? T[jl + 3][d] : (short)0;
    *(short4*)&dst[jg ^ sw] = v;
  }
}

// ---------------------------------------------------------------------------
// Kernel 3: MFMA flash attention. Deltas vs R6:
//   - double-buffered K/V/rpb tiles, ONE barrier per jt (T3 2-phase)
//   - LINEAR staging map (lane t -> byte t*16): conflict-free ds_write_b128
//     (old row/col-window map was 16-way bank-conflicted)
//   - balanced-tree softmax sum (was 16-deep serial FP chain)
// Keeps: swapped-QK in-reg softmax, exp2 domain, u8 bucket gather, bf16 ctx,
// cvtpk pack, setprio, defer-max, tail-only mask, XCD swizzle.
// ---------------------------------------------------------------------------
__launch_bounds__(256)
__global__ void attn_k(const short* __restrict__ Qbf, const short* __restrict__ Ksw,
                       const short* __restrict__ Vtsw, const float* __restrict__ rpe,
                       const unsigned char* __restrict__ rpbu8, float* __restrict__ y) {
  __shared__ short Kt[2 * 4096];              // 16 KB (double)
  __shared__ short Vt[2 * 4096];              // 16 KB (double)
  __shared__ unsigned char rpbt[2 * 5120];    // 10 KB (double); Rp unioned below
  __shared__ unsigned short ctxs[4][16][53];  // 6.6 KB (bf16 ctx, odd stride)
  short (*Rp)[64] = (short (*)[64])rpbt;      // [64][64] bf16, 8 KB, prologue only

  const int t = threadIdx.x;
  const int w = t >> 6, lane = t & 63, g = lane >> 4, ln = lane & 15;
  // XCD swizzle: all 10 q-tiles of one bh share an XCD
  const int wg = blockIdx.x;
  const int xcd = wg & 7, idx = wg >> 3;
  const int qt = idx % 10;
  const int bh = (idx / 10) * 8 + xcd;
  const int b = bh / HN_, h = bh - b * HN_;
  const int i0 = qt * 64;
  const size_t rb = (size_t)bh * SN_;
  const short* Kbh = Ksw + (size_t)bh * SP_ * 64;
  const short* Vbh = Vtsw + (size_t)bh * 64 * SP_;

  // staging maps: K linear (tile region is contiguous 8KB); V row-wise
  const int tK = t * 8;                       // shorts
  const int vRow = t >> 3, vCol = (t & 7) * 8;
  const int rpRow = t >> 2, rpCol = (t & 3) * 16;
  const int irow_s = (i0 + rpRow <= SN_ - 1) ? (i0 + rpRow) : (SN_ - 1);

  // issue tile 0 loads
  short8 kr0, kr1, vr0, vr1; int4 rp_;
  kr0 = *(const short8*)(Kbh + tK);
  kr1 = *(const short8*)(Kbh + 2048 + tK);
  vr0 = *(const short8*)(Vbh + (size_t)vRow * SP_ + vCol);
  vr1 = *(const short8*)(Vbh + (size_t)(32 + vRow) * SP_ + vCol);
  rp_ = *(const int4*)(rpbu8 + (size_t)irow_s * 640 + rpCol);

  // stage rpe^T -> Rp[c][d] (bf16), pad c>=50 with 0
  for (int e = t; e < 64 * 64; e += 256) {
    const int c = e >> 6, d = e & 63;
    Rp[c][d] = (c < NB_) ? f2bf(rpe[d * NB_ + c]) : (short)0;
  }

  // Q fragments (bf16 direct); lane holds Q row i = i0 + 16w + ln
  short8 qf[2];
  {
    int row = i0 + 16 * w + ln; if (row > SN_ - 1) row = SN_ - 1;
    const short* qp = Qbf + (rb + row) * 64;
    qf[0] = *(const short8*)(qp + 8 * g);
    qf[1] = *(const short8*)(qp + 32 + 8 * g);
  }

  __syncthreads();  // B1: Rp visible

  // ctx tile: ctx[i_local=4g+r][c=ct*16+ln] via mfma(qf, rf); store bf16
  {
    f32x4 accC[4];
#pragma unroll
    for (int ct = 0; ct < 4; ++ct) accC[ct] = (f32x4){0.f, 0.f, 0.f, 0.f};
#pragma unroll
    for (int kc = 0; kc < 2; ++kc) {
#pragma unroll
      for (int ct = 0; ct < 4; ++ct) {
        const short8 rf = *(const short8*)&Rp[ct * 16 + ln][kc * 32 + 8 * g];
        accC[ct] = __builtin_amdgcn_mfma_f32_16x16x32_bf16(qf[kc], rf, accC[ct], 0, 0, 0);
      }
    }
    __syncthreads();  // B2: all Rp reads done (rpbt region can be reused)
#pragma unroll
    for (int ct = 0; ct < 4; ++ct) {
      const int c = ct * 16 + ln;
      if (c < 53) {
#pragma unroll
        for (int r = 0; r < 4; ++r)
          ctxs[w][4 * g + r][c] = (unsigned short)f2bf(accC[ct][r]);
      }
    }
  }

  // write tile 0 -> buf0; issue tile 1
  *(short8*)&Kt[tK]        = kr0;
  *(short8*)&Kt[2048 + tK] = kr1;
  *(short8*)&Vt[tK]        = vr0;
  *(short8*)&Vt[2048 + tK] = vr1;
  *(int4*)&rpbt[rpRow * 80 + rpCol] = rp_;
  kr0 = *(const short8*)(Kbh + 4096 + tK);
  kr1 = *(const short8*)(Kbh + 4096 + 2048 + tK);
  vr0 = *(const short8*)(Vbh + (size_t)vRow * SP_ + 64 + vCol);
  vr1 = *(const short8*)(Vbh + (size_t)(32 + vRow) * SP_ + 64 + vCol);
  rp_ = *(const int4*)(rpbu8 + (size_t)irow_s * 640 + 64 + rpCol);
  __syncthreads();  // B3: buf0 visible (ctxs also visible, though same-wave)

  float m = -3e38f, l = 0.f;
  f32x4 accO[4];
#pragma unroll
  for (int dt = 0; dt < 4; ++dt) accO[dt] = (f32x4){0.f, 0.f, 0.f, 0.f};

  const int swv = (ln & 7) << 3;
  const unsigned short* cbase = &ctxs[w][ln][0];
  const int rpoff = (16 * w + ln) * 80;

  int cur = 0;
  for (int jt = 0; jt < 10; ++jt) {
    const int cw = cur ^ 1;
    // write tile jt+1 (regs) into the other buffer; its readers finished
    // before the barrier that ended jt-1.
    if (jt < 9) {
      *(short8*)&Kt[cw * 4096 + tK]        = kr0;
      *(short8*)&Kt[cw * 4096 + 2048 + tK] = kr1;
      *(short8*)&Vt[cw * 4096 + tK]        = vr0;
      *(short8*)&Vt[cw * 4096 + 2048 + tK] = vr1;
      *(int4*)&rpbt[cw * 5120 + rpRow * 80 + rpCol] = rp_;
    }
    // issue tile jt+2 loads (land during this compute + next write phase)
    if (jt < 8) {
      const int jn = jt * 64 + 128;
      kr0 = *(const short8*)(Kbh + (size_t)jn * 64 + tK);
      kr1 = *(const short8*)(Kbh + (size_t)jn * 64 + 2048 + tK);
      vr0 = *(const short8*)(Vbh + (size_t)vRow * SP_ + jn + vCol);
      vr1 = *(const short8*)(Vbh + (size_t)(32 + vRow) * SP_ + jn + vCol);
      rp_ = *(const int4*)(rpbu8 + (size_t)irow_s * 640 + jn + rpCol);
    }

    const short* KtC = Kt + cur * 4096;
    const short* VtC = Vt + cur * 4096;
    const unsigned char* rpC = rpbt + cur * 5120;

    // QK^T swapped: accS[nt][r] = S[i = ln][j = jt*64 + nt*16 + 4g + r]
    f32x4 accS[4];
#pragma unroll
    for (int nt = 0; nt < 4; ++nt) accS[nt] = (f32x4){0.f, 0.f, 0.f, 0.f};
    __builtin_amdgcn_s_setprio(1);
#pragma unroll
    for (int kc = 0; kc < 2; ++kc) {
      const int cb = (kc * 32 + 8 * g) ^ swv;
#pragma unroll
      for (int nt = 0; nt < 4; ++nt) {
        const short8 kf = *(const short8*)&KtC[(nt * 16 + ln) * 64 + cb];
        accS[nt] = __builtin_amdgcn_mfma_f32_16x16x32_bf16(kf, qf[kc], accS[nt], 0, 0, 0);
      }
    }
    __builtin_amdgcn_s_setprio(0);

    // bias (bucket gather via u8 LDS tile; bf16 ctx row ln, odd stride 53)
    float pv[4][4];
#pragma unroll
    for (int nt = 0; nt < 4; ++nt) {
      const uchar4 bk = *(const uchar4*)&rpC[rpoff + nt * 16 + 4 * g];
      pv[nt][0] = accS[nt][0] + bf2f(cbase[bk.x]);
      pv[nt][1] = accS[nt][1] + bf2f(cbase[bk.y]);
      pv[nt][2] = accS[nt][2] + bf2f(cbase[bk.z]);
      pv[nt][3] = accS[nt][3] + bf2f(cbase[bk.w]);
    }
    if (jt == 9) {  // tail: REPLACE invalid-j entries (poison-proof)
#pragma unroll
      for (int nt = 0; nt < 4; ++nt) {
        const int jb = jt * 64 + nt * 16 + 4 * g;
#pragma unroll
        for (int r = 0; r < 4; ++r)
          if (jb + r >= SN_) pv[nt][r] = -3e38f;
      }
    }

    // online softmax, in-register row (i = ln), exp2 domain; balanced trees
    float mq[4];
#pragma unroll
    for (int nt = 0; nt < 4; ++nt)
      mq[nt] = fmaxf(fmaxf(pv[nt][0], pv[nt][1]), fmaxf(pv[nt][2], pv[nt][3]));
    float mx = fmaxf(fmaxf(mq[0], mq[1]), fmaxf(mq[2], mq[3]));
    mx = fmaxf(mx, __shfl_xor(mx, 16));
    mx = fmaxf(mx, __shfl_xor(mx, 32));

    if (__any(mx > m + 8.f)) {  // rescale path (rare after first tiles)
      const float mnew = fmaxf(m, mx);
      const float sc = ex2(m - mnew);
      float scr[4];
#pragma unroll
      for (int r = 0; r < 4; ++r) scr[r] = __shfl(sc, 4 * g + r);
#pragma unroll
      for (int dt = 0; dt < 4; ++dt)
#pragma unroll
        for (int r = 0; r < 4; ++r) accO[dt][r] *= scr[r];
      l *= sc;
      m = mnew;
    }

#pragma unroll
    for (int nt = 0; nt < 4; ++nt)
#pragma unroll
      for (int r = 0; r < 4; ++r)
        pv[nt][r] = ex2(pv[nt][r] - m);
    float sq[4];
#pragma unroll
    for (int nt = 0; nt < 4; ++nt)
      sq[nt] = (pv[nt][0] + pv[nt][1]) + (pv[nt][2] + pv[nt][3]);
    float sum = (sq[0] + sq[1]) + (sq[2] + sq[3]);
    sum += __shfl_xor(sum, 16);
    sum += __shfl_xor(sum, 32);
    l += sum;

    // pack P to bf16 via v_cvt_pk (slot jj -> j = kc*32 + 16*(jj>>2) + 4g + (jj&3))
    short8 pf[2];
#pragma unroll
    for (int kc = 0; kc < 2; ++kc) {
      union { short8 v; unsigned wd[4]; } pk;
      pk.wd[0] = cvtpk(pv[2 * kc][0],     pv[2 * kc][1]);
      pk.wd[1] = cvtpk(pv[2 * kc][2],     pv[2 * kc][3]);
      pk.wd[2] = cvtpk(pv[2 * kc + 1][0], pv[2 * kc + 1][1]);
      pk.wd[3] = cvtpk(pv[2 * kc + 1][2], pv[2 * kc + 1][3]);
      pf[kc] = pk.v;
    }

    // PV: accO[dt][r] = O[i=4g+r][d=dt*16+ln]; V^T read with matching slot map
    __builtin_amdgcn_s_setprio(1);
#pragma unroll
    for (int kc = 0; kc < 2; ++kc) {
#pragma unroll
      for (int dt = 0; dt < 4; ++dt) {
        const short* vrow = &VtC[(dt * 16 + ln) * 64];
        union { short8 v; short4 hh[2]; } u;
        u.hh[0] = *(const short4*)&vrow[(kc * 32 + 4 * g) ^ swv];
        u.hh[1] = *(const short4*)&vrow[(kc * 32 + 16 + 4 * g) ^ swv];
        accO[dt] = __builtin_amdgcn_mfma_f32_16x16x32_bf16(pf[kc], u.v, accO[dt], 0, 0, 0);
      }
    }
    __builtin_amdgcn_s_setprio(0);

    __syncthreads();  // single barrier: cw writes visible, cur reads done
    cur ^= 1;
  }

  // epilogue: y[b, i, h*64 + d] = O / l   (l for row 4g+r via shfl)
  float linv[4];
#pragma unroll
  for (int r = 0; r < 4; ++r) linv[r] = 1.f / __shfl(l, 4 * g + r);
#pragma unroll
  for (int r = 0; r < 4; ++r) {
    const int i = i0 + 16 * w + 4 * g + r;
    if (i >= SN_) continue;
    float* yp = y + ((size_t)b * SN_ + i) * DN_ + h * HD_ + ln;
#pragma unroll
    for (int dt = 0; dt < 4; ++dt) yp[dt * 16] = accO[dt][r] * linv[r];
  }
}

// ---------------------------------------------------------------------------
extern "C" void kernel_launch(void* const* d_in, const int* in_sizes, int n_in,
                              void* d_out, int out_size, void* d_ws, size_t ws_size,
                              hipStream_t stream) {
  const float* x   = (const float*)d_in[0];
  const float* w   = (const float*)d_in[1];
  const float* rpe = (const float*)d_in[2];
  const int*   rpb = (const int*)d_in[3];
  float* y = (float*)d_out;

  short* xb   = (short*)d_ws;                      // 9344*768
  short* wb   = xb + (size_t)MRP_ * DN_;           // 2304*768
  short* Qbf  = wb + (size_t)NQ_ * DN_;            // 110784*64
  short* Ksw  = Qbf + (size_t)BHS_ * HD_;          // 192*640*64
  short* Vbf  = Ksw + (size_t)BN_ * HN_ * SP_ * 64;
  short* Vtsw = Vbf + (size_t)BN_ * HN_ * SP_ * 64;
  unsigned char* rpbu8 = (unsigned char*)(Vtsw + (size_t)BN_ * HN_ * 64 * SP_);  // 577*640

  cvt_k<<<dim3(MRP_ * DN_ / 2048), 256, 0, stream>>>(x, xb, MR_ * DN_, MRP_ * DN_);
  cvt_k<<<dim3(NQ_ * DN_ / 2048), 256, 0, stream>>>(w, wb, NQ_ * DN_, NQ_ * DN_);
  rpb8_k<<<dim3((SN_ * 160 + 255) / 256), 256, 0, stream>>>(rpb, rpbu8);
  qkv_mfma_k<<<dim3(18, 73), 256, 0, stream>>>(xb, wb, Qbf, Ksw, Vbf);
  vtr_k<<<dim3(10, BN_ * HN_), 256, 0, stream>>>(Vbf, Vtsw);
  attn_k<<<dim3(1920), 256, 0, stream>>>(Qbf, Ksw, Vtsw, rpe, rpbu8, y);
}

// Round 9
// 149.851 us; speedup vs baseline: 1.0848x; 1.0848x over previous
//
#include <hip/hip_runtime.h>

// Problem constants
constexpr int BN_  = 16;                 // batch
constexpr int SN_  = 577;                // seq
constexpr int SP_  = 640;                // padded seq (multiple of 64)
constexpr int DN_  = 768;                // model dim
constexpr int HN_  = 12;                 // heads
constexpr int HD_  = 64;                 // head dim
constexpr int NB_  = 50;                 // rpe buckets
constexpr int MR_  = BN_ * SN_;          // 9232 rows of x
constexpr int MRP_ = 73 * 128;           // 9344 padded rows
constexpr int NQ_  = 3 * DN_;            // 2304 qkv cols
constexpr int BHS_ = BN_ * HN_ * SN_;    // 110784 (b,h,i) rows
constexpr int SHD_ = SN_ * HD_;          // 36928

typedef __attribute__((ext_vector_type(8))) short short8;
typedef __attribute__((ext_vector_type(4))) float f32x4;

__device__ __forceinline__ short f2bf(float f) {
  union { float f; unsigned u; } v; v.f = f;
  unsigned r = (v.u + 0x7fffu + ((v.u >> 16) & 1u)) >> 16;
  return (short)r;
}

// raw v_exp_f32: D = 2^S0 (handles -3e38 -> 0)
__device__ __forceinline__ float ex2(float x) {
  float r; asm("v_exp_f32 %0, %1" : "=v"(r) : "v"(x)); return r;
}

// v_cvt_pk_bf16_f32: dst = {lo16=bf16(a), hi16=bf16(b)}
__device__ __forceinline__ unsigned cvtpk(float a, float b) {
  unsigned r; asm("v_cvt_pk_bf16_f32 %0, %1, %2" : "=v"(r) : "v"(a), "v"(b));
  return r;
}

__device__ __forceinline__ float bf2f(unsigned short u) {
  union { unsigned u; float f; } v; v.u = ((unsigned)u) << 16; return v.f;
}

// ---------------------------------------------------------------------------
// Kernel 0: f32 -> bf16 convert (pads dst beyond n_src with zeros)
// ---------------------------------------------------------------------------
__launch_bounds__(256)
__global__ void cvt_k(const float* __restrict__ src, short* __restrict__ dst,
                      int n_src, int n_dst) {
  const int i = (blockIdx.x * 256 + threadIdx.x) * 8;
  if (i >= n_dst) return;
  union { short8 v; short u[8]; } pk;
  if (i < n_src) {
    const float4 a = *(const float4*)(src + i);
    const float4 b = *(const float4*)(src + i + 4);
    pk.u[0] = f2bf(a.x); pk.u[1] = f2bf(a.y); pk.u[2] = f2bf(a.z); pk.u[3] = f2bf(a.w);
    pk.u[4] = f2bf(b.x); pk.u[5] = f2bf(b.y); pk.u[6] = f2bf(b.z); pk.u[7] = f2bf(b.w);
  } else {
#pragma unroll
    for (int j = 0; j < 8; ++j) pk.u[j] = 0;
  }
  *(short8*)(dst + i) = pk.v;
}

// ---------------------------------------------------------------------------
// Kernel 0b: rp_bucket int32 [577][577] -> u8 [577][640] (pad j with 0)
// ---------------------------------------------------------------------------
__launch_bounds__(256)
__global__ void rpb8_k(const int* __restrict__ rpb, unsigned char* __restrict__ rpbu8) {
  const int tid = blockIdx.x * 256 + threadIdx.x;
  if (tid >= SN_ * 160) return;
  const int i = tid / 160, c4 = tid - i * 160;
  const int j = c4 * 4;
  uchar4 o;
  o.x = (j     < SN_) ? (unsigned char)rpb[i * SN_ + j    ] : 0;
  o.y = (j + 1 < SN_) ? (unsigned char)rpb[i * SN_ + j + 1] : 0;
  o.z = (j + 2 < SN_) ? (unsigned char)rpb[i * SN_ + j + 2] : 0;
  o.w = (j + 3 < SN_) ? (unsigned char)rpb[i * SN_ + j + 3] : 0;
  *(uchar4*)(rpbu8 + (size_t)i * 640 + j) = o;
}

// ---------------------------------------------------------------------------
// Kernel 1: qkv = x @ w^T in bf16 MFMA (unchanged).
// ---------------------------------------------------------------------------
__launch_bounds__(256)
__global__ void qkv_mfma_k(const short* __restrict__ xb, const short* __restrict__ wb,
                           short* __restrict__ Qbf, short* __restrict__ Ksw,
                           short* __restrict__ Vbf) {
  __shared__ short At[128 * 64];
  __shared__ short Bt[128 * 64];
  const int t = threadIdx.x;
  const int w = t >> 6, lane = t & 63, g = lane >> 4, ln = lane & 15;
  const int wm = w >> 1, wn = w & 1;
  const int m0 = blockIdx.y * 128, n0 = blockIdx.x * 128;

  const int sr = t >> 1, su = (t & 1) * 4;
  const short* ga = xb + (size_t)(m0 + sr) * DN_ + su * 8;
  const short* gb = wb + (size_t)(n0 + sr) * DN_ + su * 8;
  short* la = At + sr * 64;
  short* lb = Bt + sr * 64;
  const int swr = sr & 7;

  f32x4 acc[4][4];
#pragma unroll
  for (int mt = 0; mt < 4; ++mt)
#pragma unroll
    for (int nt = 0; nt < 4; ++nt) acc[mt][nt] = (f32x4){0.f, 0.f, 0.f, 0.f};

  short8 ra[4], rb[4];
#pragma unroll
  for (int u = 0; u < 4; ++u) {
    ra[u] = *(const short8*)(ga + u * 8);
    rb[u] = *(const short8*)(gb + u * 8);
  }

  for (int k0 = 0; k0 < DN_; k0 += 64) {
    __syncthreads();
#pragma unroll
    for (int u = 0; u < 4; ++u) {
      *(short8*)(la + (((su + u) ^ swr) * 8)) = ra[u];
      *(short8*)(lb + (((su + u) ^ swr) * 8)) = rb[u];
    }
    __syncthreads();
    if (k0 + 64 < DN_) {
#pragma unroll
      for (int u = 0; u < 4; ++u) {
        ra[u] = *(const short8*)(ga + k0 + 64 + u * 8);
        rb[u] = *(const short8*)(gb + k0 + 64 + u * 8);
      }
    }
#pragma unroll
    for (int kc = 0; kc < 2; ++kc) {
      short8 af[4], bf[4];
#pragma unroll
      for (int mt = 0; mt < 4; ++mt) {
        const int row = wm * 64 + mt * 16 + ln;
        const int u = (kc * 4 + g) ^ (row & 7);
        af[mt] = *(const short8*)&At[row * 64 + u * 8];
      }
#pragma unroll
      for (int nt = 0; nt < 4; ++nt) {
        const int row = wn * 64 + nt * 16 + ln;
        const int u = (kc * 4 + g) ^ (row & 7);
        bf[nt] = *(const short8*)&Bt[row * 64 + u * 8];
      }
#pragma unroll
      for (int mt = 0; mt < 4; ++mt)
#pragma unroll
        for (int nt = 0; nt < 4; ++nt)
          acc[mt][nt] = __builtin_amdgcn_mfma_f32_16x16x32_bf16(af[mt], bf[nt], acc[mt][nt], 0, 0, 0);
    }
  }

  const int nw0  = n0 + wn * 64;
  const int secg = nw0 / DN_;
  const int cbw  = nw0 - secg * DN_;
  const float QSC = 0.18033688011112042f;   // log2(e) / 8
#pragma unroll
  for (int mt = 0; mt < 4; ++mt) {
#pragma unroll
    for (int r = 0; r < 4; ++r) {
      const int gm = m0 + wm * 64 + mt * 16 + 4 * g + r;
      if (gm >= MR_) continue;
      const int bb = gm / SN_;
      const int ss = gm - bb * SN_;
      const int pb = ss * DN_ + cbw;
#pragma unroll
      for (int nt = 0; nt < 4; ++nt) {
        const int p   = pb + nt * 16 + ln;
        const int hh  = p / SHD_;
        const int rem = p - hh * SHD_;
        const int ii  = rem >> 6;
        const int dd  = rem & 63;
        const size_t ro = (size_t)(bb * HN_ + hh);
        const float v = acc[mt][nt][r];
        if (secg == 0) {
          Qbf[(ro * SN_ + ii) * 64 + dd] = f2bf(v * QSC);
        } else if (secg == 1) {
          Ksw[(ro * SP_ + ii) * 64 + (dd ^ ((ii & 7) << 3))] = f2bf(v);
        } else {
          Vbf[(ro * SP_ + ii) * 64 + dd] = f2bf(v);
        }
      }
    }
  }
}

// ---------------------------------------------------------------------------
// Kernel 2: transpose V per (bh): Vbf[j][d] -> Vtsw[d][pi(j)], bf16.
// pi permutes quads within each 32-col block: oq -> 2*(oq&3) + (oq>>2),
// so the attention PV custom slot map reads ONE contiguous b128 per frag.
// Then XOR-swizzle on 8-short units with (d&7). Pad cols j>=577 zeroed.
// ---------------------------------------------------------------------------
__launch_bounds__(256)
__global__ void vtr_k(const short* __restrict__ Vbf, short* __restrict__ Vtsw) {
  __shared__ short T[64][72];
  const int t = threadIdx.x;
  const int jt = blockIdx.x, bh = blockIdx.y;
  const int j0 = jt * 64;
  {
    const int r = t >> 2, c0 = (t & 3) * 16;
    const short* src = Vbf + ((size_t)bh * SP_ + j0 + r) * 64 + c0;
    *(short8*)&T[r][c0]     = *(const short8*)(src);
    *(short8*)&T[r][c0 + 8] = *(const short8*)(src + 8);
  }
  __syncthreads();
  const int d = t >> 2;
  short* dst = Vtsw + ((size_t)bh * 64 + d) * SP_;
  const int sw = (d & 7) << 3;
#pragma unroll
  for (int e = 0; e < 4; ++e) {
    const int jl = (t & 3) * 16 + e * 4;
    const int jg = j0 + jl;
    short4 v;
    v.x = (jg + 0 < SN_) ? T[jl + 0][d] : (short)0;
    v.y = (jg + 1 < SN_) ? T[jl + 1][d] : (short)0;
    v.z = (jg + 2 < SN_) ? T[jl + 2][d] : (short)0;
    v.w = (jg + 3 < SN_) ? T[jl + 3][d] : (short)0;
    const int oq = (jg >> 2) & 7;
    const int pq = ((oq & 3) << 1) | (oq >> 2);
    const int p  = (jg & ~31) | (pq << 2);
    *(short4*)&dst[p ^ sw] = v;
  }
}

// ---------------------------------------------------------------------------
// Kernel 3: MFMA flash attention. q-tile 128: 4 waves x 32 q-rows (2 sets of
// 16). K/V fragments shared by both sets -> LDS reads per q-row halved; V
// permuted in global so PV frags are single b128 (like K). Single-buffered
// K/V/rpb, 2 barriers/jt, reg prefetch. Swapped-QK in-reg softmax, exp2,
// u8 buckets, bf16 ctx, cvtpk pack, setprio, defer-max, XCD swizzle.
// ---------------------------------------------------------------------------
__launch_bounds__(256)
__global__ void attn_k(const short* __restrict__ Qbf, const short* __restrict__ Ksw,
                       const short* __restrict__ Vtsw, const float* __restrict__ rpe,
                       const unsigned char* __restrict__ rpbu8, float* __restrict__ y) {
  __shared__ short Kt[4096];                  // 8 KB
  __shared__ short Vt[4096];                  // 8 KB
  __shared__ unsigned char rpbt[128 * 68];    // 8.5 KB; unioned with Rp (8 KB)
  __shared__ unsigned short ctxs[4][32][53];  // 13.25 KB bf16
  short (*Rp)[64] = (short (*)[64])rpbt;

  const int t = threadIdx.x;
  const int w = t >> 6, lane = t & 63, g = lane >> 4, ln = lane & 15;
  // XCD swizzle: all 5 q-tiles of one bh share an XCD
  const int wg = blockIdx.x;
  const int xcd = wg & 7, idx = wg >> 3;
  const int qt = idx % 5;
  const int bh = (idx / 5) * 8 + xcd;
  const int b = bh / HN_, h = bh - b * HN_;
  const int i0 = qt * 128;
  const size_t rb = (size_t)bh * SN_;
  const short* Kbh = Ksw + (size_t)bh * SP_ * 64;
  const short* Vbh = Vtsw + (size_t)bh * 64 * SP_;

  // staging maps
  const int tK = t * 8;                          // K/V: linear, 2x 16B
  const int vRow = t >> 3, vCol = (t & 7) * 8;   // V global rows
  const int rpRow = t >> 1, rpCol = (t & 1) * 32;  // rpb: 128 rows x 32B
  const int irow_s = (i0 + rpRow <= SN_ - 1) ? (i0 + rpRow) : (SN_ - 1);

  // issue tile 0 loads
  short8 kr0, kr1, vr0, vr1; int4 rp0_, rp1_;
  kr0 = *(const short8*)(Kbh + tK);
  kr1 = *(const short8*)(Kbh + 2048 + tK);
  vr0 = *(const short8*)(Vbh + (size_t)vRow * SP_ + vCol);
  vr1 = *(const short8*)(Vbh + (size_t)(32 + vRow) * SP_ + vCol);
  rp0_ = *(const int4*)(rpbu8 + (size_t)irow_s * 640 + rpCol);
  rp1_ = *(const int4*)(rpbu8 + (size_t)irow_s * 640 + rpCol + 16);

  // stage rpe^T -> Rp[c][d] (bf16), pad c>=50 with 0
  for (int e = t; e < 64 * 64; e += 256) {
    const int c = e >> 6, d = e & 63;
    Rp[c][d] = (c < NB_) ? f2bf(rpe[d * NB_ + c]) : (short)0;
  }

  // Q fragments, 2 sets: set s covers rows i0 + 32w + 16s + ln
  short8 qf[2][2];
#pragma unroll
  for (int s = 0; s < 2; ++s) {
    int row = i0 + 32 * w + 16 * s + ln; if (row > SN_ - 1) row = SN_ - 1;
    const short* qp = Qbf + (rb + row) * 64;
    qf[s][0] = *(const short8*)(qp + 8 * g);
    qf[s][1] = *(const short8*)(qp + 32 + 8 * g);
  }

  __syncthreads();  // B1: Rp visible

  // ctx tiles (both sets): ctx[32w+16s+4g+r][c=ct*16+ln]
  {
    f32x4 accC[2][4];
#pragma unroll
    for (int s = 0; s < 2; ++s)
#pragma unroll
      for (int ct = 0; ct < 4; ++ct) accC[s][ct] = (f32x4){0.f, 0.f, 0.f, 0.f};
#pragma unroll
    for (int kc = 0; kc < 2; ++kc) {
#pragma unroll
      for (int ct = 0; ct < 4; ++ct) {
        const short8 rf = *(const short8*)&Rp[ct * 16 + ln][kc * 32 + 8 * g];
        accC[0][ct] = __builtin_amdgcn_mfma_f32_16x16x32_bf16(qf[0][kc], rf, accC[0][ct], 0, 0, 0);
        accC[1][ct] = __builtin_amdgcn_mfma_f32_16x16x32_bf16(qf[1][kc], rf, accC[1][ct], 0, 0, 0);
      }
    }
#pragma unroll
    for (int s = 0; s < 2; ++s)
#pragma unroll
      for (int ct = 0; ct < 4; ++ct) {
        const int c = ct * 16 + ln;
        if (c < 53) {
#pragma unroll
          for (int r = 0; r < 4; ++r)
            ctxs[w][16 * s + 4 * g + r][c] = (unsigned short)f2bf(accC[s][ct][r]);
        }
      }
  }

  float m0s = -3e38f, m1s = -3e38f, l0s = 0.f, l1s = 0.f;
  f32x4 accO[2][4];
#pragma unroll
  for (int s = 0; s < 2; ++s)
#pragma unroll
    for (int dt = 0; dt < 4; ++dt) accO[s][dt] = (f32x4){0.f, 0.f, 0.f, 0.f};

  const int swv = (ln & 7) << 3;

  for (int jt = 0; jt < 10; ++jt) {
    __syncthreads();  // B_a: previous compute's LDS reads (and Rp reads) done
    *(short8*)&Kt[tK]        = kr0;
    *(short8*)&Kt[2048 + tK] = kr1;
    *(short8*)&Vt[tK]        = vr0;
    *(short8*)&Vt[2048 + tK] = vr1;
    *(int4*)&rpbt[rpRow * 68 + rpCol]      = rp0_;
    *(int4*)&rpbt[rpRow * 68 + rpCol + 16] = rp1_;
    __syncthreads();  // B_b: tiles visible

    if (jt < 9) {  // prefetch next tile
      const int jn = jt * 64 + 64;
      kr0 = *(const short8*)(Kbh + (size_t)jn * 64 + tK);
      kr1 = *(const short8*)(Kbh + (size_t)jn * 64 + 2048 + tK);
      vr0 = *(const short8*)(Vbh + (size_t)vRow * SP_ + jn + vCol);
      vr1 = *(const short8*)(Vbh + (size_t)(32 + vRow) * SP_ + jn + vCol);
      rp0_ = *(const int4*)(rpbu8 + (size_t)irow_s * 640 + jn + rpCol);
      rp1_ = *(const int4*)(rpbu8 + (size_t)irow_s * 640 + jn + rpCol + 16);
    }

    // QK^T both sets (K frags shared): accS[s][nt][r] = S_s[i=ln][j=nt*16+4g+r]
    f32x4 accS[2][4];
#pragma unroll
    for (int s = 0; s < 2; ++s)
#pragma unroll
      for (int nt = 0; nt < 4; ++nt) accS[s][nt] = (f32x4){0.f, 0.f, 0.f, 0.f};
    __builtin_amdgcn_s_setprio(1);
#pragma unroll
    for (int kc = 0; kc < 2; ++kc) {
      const int cb = (kc * 32 + 8 * g) ^ swv;
#pragma unroll
      for (int nt = 0; nt < 4; ++nt) {
        const short8 kf = *(const short8*)&Kt[(nt * 16 + ln) * 64 + cb];
        accS[0][nt] = __builtin_amdgcn_mfma_f32_16x16x32_bf16(kf, qf[0][kc], accS[0][nt], 0, 0, 0);
        accS[1][nt] = __builtin_amdgcn_mfma_f32_16x16x32_bf16(kf, qf[1][kc], accS[1][nt], 0, 0, 0);
      }
    }
    __builtin_amdgcn_s_setprio(0);

    // per set: bias + softmax + pack
    short8 pf[2][2];
#pragma unroll
    for (int s = 0; s < 2; ++s) {
      const unsigned short* cbase = &ctxs[w][16 * s + ln][0];
      const int rpoff = (32 * w + 16 * s + ln) * 68;
      float pv[4][4];
#pragma unroll
      for (int nt = 0; nt < 4; ++nt) {
        const uchar4 bk = *(const uchar4*)&rpbt[rpoff + nt * 16 + 4 * g];
        pv[nt][0] = accS[s][nt][0] + bf2f(cbase[bk.x]);
        pv[nt][1] = accS[s][nt][1] + bf2f(cbase[bk.y]);
        pv[nt][2] = accS[s][nt][2] + bf2f(cbase[bk.z]);
        pv[nt][3] = accS[s][nt][3] + bf2f(cbase[bk.w]);
      }
      if (jt == 9) {  // tail: REPLACE invalid-j entries (poison-proof)
#pragma unroll
        for (int nt = 0; nt < 4; ++nt) {
          const int jb = jt * 64 + nt * 16 + 4 * g;
#pragma unroll
          for (int r = 0; r < 4; ++r)
            if (jb + r >= SN_) pv[nt][r] = -3e38f;
        }
      }

      float& m = (s == 0) ? m0s : m1s;
      float& l = (s == 0) ? l0s : l1s;

      float mq[4];
#pragma unroll
      for (int nt = 0; nt < 4; ++nt)
        mq[nt] = fmaxf(fmaxf(pv[nt][0], pv[nt][1]), fmaxf(pv[nt][2], pv[nt][3]));
      float mx = fmaxf(fmaxf(mq[0], mq[1]), fmaxf(mq[2], mq[3]));
      mx = fmaxf(mx, __shfl_xor(mx, 16));
      mx = fmaxf(mx, __shfl_xor(mx, 32));

      if (__any(mx > m + 8.f)) {
        const float mnew = fmaxf(m, mx);
        const float sc = ex2(m - mnew);
        float scr[4];
#pragma unroll
        for (int r = 0; r < 4; ++r) scr[r] = __shfl(sc, 4 * g + r);
#pragma unroll
        for (int dt = 0; dt < 4; ++dt)
#pragma unroll
          for (int r = 0; r < 4; ++r) accO[s][dt][r] *= scr[r];
        l *= sc;
        m = mnew;
      }

#pragma unroll
      for (int nt = 0; nt < 4; ++nt)
#pragma unroll
        for (int r = 0; r < 4; ++r)
          pv[nt][r] = ex2(pv[nt][r] - m);
      float sq[4];
#pragma unroll
      for (int nt = 0; nt < 4; ++nt)
        sq[nt] = (pv[nt][0] + pv[nt][1]) + (pv[nt][2] + pv[nt][3]);
      float sum = (sq[0] + sq[1]) + (sq[2] + sq[3]);
      sum += __shfl_xor(sum, 16);
      sum += __shfl_xor(sum, 32);
      l += sum;

#pragma unroll
      for (int kc = 0; kc < 2; ++kc) {
        union { short8 v; unsigned wd[4]; } pk;
        pk.wd[0] = cvtpk(pv[2 * kc][0],     pv[2 * kc][1]);
        pk.wd[1] = cvtpk(pv[2 * kc][2],     pv[2 * kc][3]);
        pk.wd[2] = cvtpk(pv[2 * kc + 1][0], pv[2 * kc + 1][1]);
        pk.wd[3] = cvtpk(pv[2 * kc + 1][2], pv[2 * kc + 1][3]);
        pf[s][kc] = pk.v;
      }
    }

    // PV both sets (V frags shared, single b128 each thanks to permuted V)
    __builtin_amdgcn_s_setprio(1);
#pragma unroll
    for (int kc = 0; kc < 2; ++kc) {
      const int cb = (kc * 32 + 8 * g) ^ swv;
#pragma unroll
      for (int dt = 0; dt < 4; ++dt) {
        const short8 vf = *(const short8*)&Vt[(dt * 16 + ln) * 64 + cb];
        accO[0][dt] = __builtin_amdgcn_mfma_f32_16x16x32_bf16(pf[0][kc], vf, accO[0][dt], 0, 0, 0);
        accO[1][dt] = __builtin_amdgcn_mfma_f32_16x16x32_bf16(pf[1][kc], vf, accO[1][dt], 0, 0, 0);
      }
    }
    __builtin_amdgcn_s_setprio(0);
  }

  // epilogue: y[b, i, h*64 + d] = O / l
#pragma unroll
  for (int s = 0; s < 2; ++s) {
    const float lv = (s == 0) ? l0s : l1s;
    float linv[4];
#pragma unroll
    for (int r = 0; r < 4; ++r) linv[r] = 1.f / __shfl(lv, 4 * g + r);
#pragma unroll
    for (int r = 0; r < 4; ++r) {
      const int i = i0 + 32 * w + 16 * s + 4 * g + r;
      if (i >= SN_) continue;
      float* yp = y + ((size_t)b * SN_ + i) * DN_ + h * HD_ + ln;
#pragma unroll
      for (int dt = 0; dt < 4; ++dt) yp[dt * 16] = accO[s][dt][r] * linv[r];
    }
  }
}

// ---------------------------------------------------------------------------
extern "C" void kernel_launch(void* const* d_in, const int* in_sizes, int n_in,
                              void* d_out, int out_size, void* d_ws, size_t ws_size,
                              hipStream_t stream) {
  const float* x   = (const float*)d_in[0];
  const float* w   = (const float*)d_in[1];
  const float* rpe = (const float*)d_in[2];
  const int*   rpb = (const int*)d_in[3];
  float* y = (float*)d_out;

  short* xb   = (short*)d_ws;                      // 9344*768
  short* wb   = xb + (size_t)MRP_ * DN_;           // 2304*768
  short* Qbf  = wb + (size_t)NQ_ * DN_;            // 110784*64
  short* Ksw  = Qbf + (size_t)BHS_ * HD_;          // 192*640*64
  short* Vbf  = Ksw + (size_t)BN_ * HN_ * SP_ * 64;
  short* Vtsw = Vbf + (size_t)BN_ * HN_ * SP_ * 64;
  unsigned char* rpbu8 = (unsigned char*)(Vtsw + (size_t)BN_ * HN_ * 64 * SP_);  // 577*640

  cvt_k<<<dim3(MRP_ * DN_ / 2048), 256, 0, stream>>>(x, xb, MR_ * DN_, MRP_ * DN_);
  cvt_k<<<dim3(NQ_ * DN_ / 2048), 256, 0, stream>>>(w, wb, NQ_ * DN_, NQ_ * DN_);
  rpb8_k<<<dim3((SN_ * 160 + 255) / 256), 256, 0, stream>>>(rpb, rpbu8);
  qkv_mfma_k<<<dim3(18, 73), 256, 0, stream>>>(xb, wb, Qbf, Ksw, Vbf);
  vtr_k<<<dim3(10, BN_ * HN_), 256, 0, stream>>>(Vbf, Vtsw);
  attn_k<<<dim3(960), 256, 0, stream>>>(Qbf, Ksw, Vtsw, rpe, rpbu8, y);
}

// Round 10
// 148.278 us; speedup vs baseline: 1.0963x; 1.0106x over previous
//
#include <hip/hip_runtime.h>

// Problem constants
constexpr int BN_  = 16;                 // batch
constexpr int SN_  = 577;                // seq
constexpr int SP_  = 640;                // padded seq (multiple of 64)
constexpr int DN_  = 768;                // model dim
constexpr int HN_  = 12;                 // heads
constexpr int HD_  = 64;                 // head dim
constexpr int NB_  = 50;                 // rpe buckets
constexpr int MR_  = BN_ * SN_;          // 9232 rows of x
constexpr int MRP_ = 73 * 128;           // 9344 padded rows
constexpr int NQ_  = 3 * DN_;            // 2304 qkv cols
constexpr int BHS_ = BN_ * HN_ * SN_;    // 110784 (b,h,i) rows
constexpr int SHD_ = SN_ * HD_;          // 36928

typedef __attribute__((ext_vector_type(8))) short short8;
typedef __attribute__((ext_vector_type(4))) float f32x4;

__device__ __forceinline__ short f2bf(float f) {
  union { float f; unsigned u; } v; v.f = f;
  unsigned r = (v.u + 0x7fffu + ((v.u >> 16) & 1u)) >> 16;
  return (short)r;
}

// raw v_exp_f32: D = 2^S0 (handles -3e38 -> 0)
__device__ __forceinline__ float ex2(float x) {
  float r; asm("v_exp_f32 %0, %1" : "=v"(r) : "v"(x)); return r;
}

// v_cvt_pk_bf16_f32: dst = {lo16=bf16(a), hi16=bf16(b)}
__device__ __forceinline__ unsigned cvtpk(float a, float b) {
  unsigned r; asm("v_cvt_pk_bf16_f32 %0, %1, %2" : "=v"(r) : "v"(a), "v"(b));
  return r;
}

__device__ __forceinline__ float bf2f(unsigned short u) {
  union { unsigned u; float f; } v; v.u = ((unsigned)u) << 16; return v.f;
}

// async global->LDS, 16B per lane; LDS dest is wave-uniform base + lane*16
__device__ __forceinline__ void gload16(const void* g, void* l) {
  __builtin_amdgcn_global_load_lds(
      (const __attribute__((address_space(1))) unsigned int*)g,
      (__attribute__((address_space(3))) unsigned int*)l, 16, 0, 0);
}

// ---------------------------------------------------------------------------
// Kernel 0: f32 -> bf16 convert (pads dst beyond n_src with zeros)
// ---------------------------------------------------------------------------
__launch_bounds__(256)
__global__ void cvt_k(const float* __restrict__ src, short* __restrict__ dst,
                      int n_src, int n_dst) {
  const int i = (blockIdx.x * 256 + threadIdx.x) * 8;
  if (i >= n_dst) return;
  union { short8 v; short u[8]; } pk;
  if (i < n_src) {
    const float4 a = *(const float4*)(src + i);
    const float4 b = *(const float4*)(src + i + 4);
    pk.u[0] = f2bf(a.x); pk.u[1] = f2bf(a.y); pk.u[2] = f2bf(a.z); pk.u[3] = f2bf(a.w);
    pk.u[4] = f2bf(b.x); pk.u[5] = f2bf(b.y); pk.u[6] = f2bf(b.z); pk.u[7] = f2bf(b.w);
  } else {
#pragma unroll
    for (int j = 0; j < 8; ++j) pk.u[j] = 0;
  }
  *(short8*)(dst + i) = pk.v;
}

// ---------------------------------------------------------------------------
// Kernel 0b: rp_bucket int32 [577][577] -> u8 [577][640] (pad j with 0)
// ---------------------------------------------------------------------------
__launch_bounds__(256)
__global__ void rpb8_k(const int* __restrict__ rpb, unsigned char* __restrict__ rpbu8) {
  const int tid = blockIdx.x * 256 + threadIdx.x;
  if (tid >= SN_ * 160) return;
  const int i = tid / 160, c4 = tid - i * 160;
  const int j = c4 * 4;
  uchar4 o;
  o.x = (j     < SN_) ? (unsigned char)rpb[i * SN_ + j    ] : 0;
  o.y = (j + 1 < SN_) ? (unsigned char)rpb[i * SN_ + j + 1] : 0;
  o.z = (j + 2 < SN_) ? (unsigned char)rpb[i * SN_ + j + 2] : 0;
  o.w = (j + 3 < SN_) ? (unsigned char)rpb[i * SN_ + j + 3] : 0;
  *(uchar4*)(rpbu8 + (size_t)i * 640 + j) = o;
}

// ---------------------------------------------------------------------------
// Kernel 1: qkv = x @ w^T in bf16 MFMA. 128x128 tile, BK=64, 4 waves (2x2).
// Staging via global_load_lds width=16 (no VGPR round-trip, no ds_writes):
// per-lane global source is PRE-SWIZZLED so linear LDS dest reproduces the
// XOR-swizzled layout LDS[row][u] = G[row][u^(row&7)] -> frag reads unchanged.
// Epilogue scatters (torch-faithful reshape) into Q/K/V.
// ---------------------------------------------------------------------------
__launch_bounds__(256)
__global__ void qkv_mfma_k(const short* __restrict__ xb, const short* __restrict__ wb,
                           short* __restrict__ Qbf, short* __restrict__ Ksw,
                           short* __restrict__ Vbf) {
  __shared__ short At[128 * 64];
  __shared__ short Bt[128 * 64];
  const int t = threadIdx.x;
  const int w = t >> 6, lane = t & 63, g = lane >> 4, ln = lane & 15;
  const int wm = w >> 1, wn = w & 1;
  const int m0 = blockIdx.y * 128, n0 = blockIdx.x * 128;

  // gload16 maps: wave w, chunk q (0..3) covers rows w*32+q*8 .. +8.
  // lane l -> row_local = base + (l>>3), global unit gu = (l&7)^(l>>3).
  const int rlo = lane >> 3;
  const int gu  = (lane & 7) ^ rlo;
  const short* ga[4]; const short* gb[4];
  short* la[4]; short* lb[4];
#pragma unroll
  for (int q = 0; q < 4; ++q) {
    const int rl = w * 32 + q * 8 + rlo;
    ga[q] = xb + (size_t)(m0 + rl) * DN_ + gu * 8;
    gb[q] = wb + (size_t)(n0 + rl) * DN_ + gu * 8;
    la[q] = At + w * 2048 + q * 512;   // wave-uniform LDS base (shorts)
    lb[q] = Bt + w * 2048 + q * 512;
  }

  f32x4 acc[4][4];
#pragma unroll
  for (int mt = 0; mt < 4; ++mt)
#pragma unroll
    for (int nt = 0; nt < 4; ++nt) acc[mt][nt] = (f32x4){0.f, 0.f, 0.f, 0.f};

  for (int k0 = 0; k0 < DN_; k0 += 64) {
    __syncthreads();  // prior iteration's frag reads complete
#pragma unroll
    for (int q = 0; q < 4; ++q) {
      gload16(ga[q] + k0, la[q]);
      gload16(gb[q] + k0, lb[q]);
    }
    __syncthreads();  // drains vmcnt(0): tiles visible
#pragma unroll
    for (int kc = 0; kc < 2; ++kc) {
      short8 af[4], bf[4];
#pragma unroll
      for (int mt = 0; mt < 4; ++mt) {
        const int row = wm * 64 + mt * 16 + ln;
        const int u = (kc * 4 + g) ^ (row & 7);
        af[mt] = *(const short8*)&At[row * 64 + u * 8];
      }
#pragma unroll
      for (int nt = 0; nt < 4; ++nt) {
        const int row = wn * 64 + nt * 16 + ln;
        const int u = (kc * 4 + g) ^ (row & 7);
        bf[nt] = *(const short8*)&Bt[row * 64 + u * 8];
      }
#pragma unroll
      for (int mt = 0; mt < 4; ++mt)
#pragma unroll
        for (int nt = 0; nt < 4; ++nt)
          acc[mt][nt] = __builtin_amdgcn_mfma_f32_16x16x32_bf16(af[mt], bf[nt], acc[mt][nt], 0, 0, 0);
    }
  }

  const int nw0  = n0 + wn * 64;
  const int secg = nw0 / DN_;
  const int cbw  = nw0 - secg * DN_;
  const float QSC = 0.18033688011112042f;   // log2(e) / 8
#pragma unroll
  for (int mt = 0; mt < 4; ++mt) {
#pragma unroll
    for (int r = 0; r < 4; ++r) {
      const int gm = m0 + wm * 64 + mt * 16 + 4 * g + r;
      if (gm >= MR_) continue;
      const int bb = gm / SN_;
      const int ss = gm - bb * SN_;
      const int pb = ss * DN_ + cbw;
#pragma unroll
      for (int nt = 0; nt < 4; ++nt) {
        const int p   = pb + nt * 16 + ln;
        const int hh  = p / SHD_;
        const int rem = p - hh * SHD_;
        const int ii  = rem >> 6;
        const int dd  = rem & 63;
        const size_t ro = (size_t)(bb * HN_ + hh);
        const float v = acc[mt][nt][r];
        if (secg == 0) {
          Qbf[(ro * SN_ + ii) * 64 + dd] = f2bf(v * QSC);
        } else if (secg == 1) {
          Ksw[(ro * SP_ + ii) * 64 + (dd ^ ((ii & 7) << 3))] = f2bf(v);
        } else {
          Vbf[(ro * SP_ + ii) * 64 + dd] = f2bf(v);
        }
      }
    }
  }
}

// ---------------------------------------------------------------------------
// Kernel 2: transpose V per (bh): Vbf[j][d] -> Vtsw[d][pi(j)], bf16.
// pi permutes quads within each 32-col block: oq -> 2*(oq&3) + (oq>>2),
// so the attention PV custom slot map reads ONE contiguous b128 per frag.
// Then XOR-swizzle on 8-short units with (d&7). Pad cols j>=577 zeroed.
// ---------------------------------------------------------------------------
__launch_bounds__(256)
__global__ void vtr_k(const short* __restrict__ Vbf, short* __restrict__ Vtsw) {
  __shared__ short T[64][72];
  const int t = threadIdx.x;
  const int jt = blockIdx.x, bh = blockIdx.y;
  const int j0 = jt * 64;
  {
    const int r = t >> 2, c0 = (t & 3) * 16;
    const short* src = Vbf + ((size_t)bh * SP_ + j0 + r) * 64 + c0;
    *(short8*)&T[r][c0]     = *(const short8*)(src);
    *(short8*)&T[r][c0 + 8] = *(const short8*)(src + 8);
  }
  __syncthreads();
  const int d = t >> 2;
  short* dst = Vtsw + ((size_t)bh * 64 + d) * SP_;
  const int sw = (d & 7) << 3;
#pragma unroll
  for (int e = 0; e < 4; ++e) {
    const int jl = (t & 3) * 16 + e * 4;
    const int jg = j0 + jl;
    short4 v;
    v.x = (jg + 0 < SN_) ? T[jl + 0][d] : (short)0;
    v.y = (jg + 1 < SN_) ? T[jl + 1][d] : (short)0;
    v.z = (jg + 2 < SN_) ? T[jl + 2][d] : (short)0;
    v.w = (jg + 3 < SN_) ? T[jl + 3][d] : (short)0;
    const int oq = (jg >> 2) & 7;
    const int pq = ((oq & 3) << 1) | (oq >> 2);
    const int p  = (jg & ~31) | (pq << 2);
    *(short4*)&dst[p ^ sw] = v;
  }
}

// ---------------------------------------------------------------------------
// Kernel 3: MFMA flash attention (unchanged from R8). q-tile 128: 4 waves x
// 32 q-rows (2 sets of 16). K/V frags shared by both sets; permuted V ->
// single-b128 PV frags. Swapped-QK in-reg softmax, exp2, u8 buckets, bf16
// ctx, cvtpk pack, setprio, defer-max, XCD swizzle.
// ---------------------------------------------------------------------------
__launch_bounds__(256)
__global__ void attn_k(const short* __restrict__ Qbf, const short* __restrict__ Ksw,
                       const short* __restrict__ Vtsw, const float* __restrict__ rpe,
                       const unsigned char* __restrict__ rpbu8, float* __restrict__ y) {
  __shared__ short Kt[4096];                  // 8 KB
  __shared__ short Vt[4096];                  // 8 KB
  __shared__ unsigned char rpbt[128 * 68];    // 8.5 KB; unioned with Rp (8 KB)
  __shared__ unsigned short ctxs[4][32][53];  // 13.25 KB bf16
  short (*Rp)[64] = (short (*)[64])rpbt;

  const int t = threadIdx.x;
  const int w = t >> 6, lane = t & 63, g = lane >> 4, ln = lane & 15;
  // XCD swizzle: all 5 q-tiles of one bh share an XCD
  const int wg = blockIdx.x;
  const int xcd = wg & 7, idx = wg >> 3;
  const int qt = idx % 5;
  const int bh = (idx / 5) * 8 + xcd;
  const int b = bh / HN_, h = bh - b * HN_;
  const int i0 = qt * 128;
  const size_t rb = (size_t)bh * SN_;
  const short* Kbh = Ksw + (size_t)bh * SP_ * 64;
  const short* Vbh = Vtsw + (size_t)bh * 64 * SP_;

  // staging maps
  const int tK = t * 8;                          // K/V: linear, 2x 16B
  const int vRow = t >> 3, vCol = (t & 7) * 8;   // V global rows
  const int rpRow = t >> 1, rpCol = (t & 1) * 32;  // rpb: 128 rows x 32B
  const int irow_s = (i0 + rpRow <= SN_ - 1) ? (i0 + rpRow) : (SN_ - 1);

  // issue tile 0 loads
  short8 kr0, kr1, vr0, vr1; int4 rp0_, rp1_;
  kr0 = *(const short8*)(Kbh + tK);
  kr1 = *(const short8*)(Kbh + 2048 + tK);
  vr0 = *(const short8*)(Vbh + (size_t)vRow * SP_ + vCol);
  vr1 = *(const short8*)(Vbh + (size_t)(32 + vRow) * SP_ + vCol);
  rp0_ = *(const int4*)(rpbu8 + (size_t)irow_s * 640 + rpCol);
  rp1_ = *(const int4*)(rpbu8 + (size_t)irow_s * 640 + rpCol + 16);

  // stage rpe^T -> Rp[c][d] (bf16), pad c>=50 with 0
  for (int e = t; e < 64 * 64; e += 256) {
    const int c = e >> 6, d = e & 63;
    Rp[c][d] = (c < NB_) ? f2bf(rpe[d * NB_ + c]) : (short)0;
  }

  // Q fragments, 2 sets: set s covers rows i0 + 32w + 16s + ln
  short8 qf[2][2];
#pragma unroll
  for (int s = 0; s < 2; ++s) {
    int row = i0 + 32 * w + 16 * s + ln; if (row > SN_ - 1) row = SN_ - 1;
    const short* qp = Qbf + (rb + row) * 64;
    qf[s][0] = *(const short8*)(qp + 8 * g);
    qf[s][1] = *(const short8*)(qp + 32 + 8 * g);
  }

  __syncthreads();  // B1: Rp visible

  // ctx tiles (both sets): ctx[32w+16s+4g+r][c=ct*16+ln]
  {
    f32x4 accC[2][4];
#pragma unroll
    for (int s = 0; s < 2; ++s)
#pragma unroll
      for (int ct = 0; ct < 4; ++ct) accC[s][ct] = (f32x4){0.f, 0.f, 0.f, 0.f};
#pragma unroll
    for (int kc = 0; kc < 2; ++kc) {
#pragma unroll
      for (int ct = 0; ct < 4; ++ct) {
        const short8 rf = *(const short8*)&Rp[ct * 16 + ln][kc * 32 + 8 * g];
        accC[0][ct] = __builtin_amdgcn_mfma_f32_16x16x32_bf16(qf[0][kc], rf, accC[0][ct], 0, 0, 0);
        accC[1][ct] = __builtin_amdgcn_mfma_f32_16x16x32_bf16(qf[1][kc], rf, accC[1][ct], 0, 0, 0);
      }
    }
#pragma unroll
    for (int s = 0; s < 2; ++s)
#pragma unroll
      for (int ct = 0; ct < 4; ++ct) {
        const int c = ct * 16 + ln;
        if (c < 53) {
#pragma unroll
          for (int r = 0; r < 4; ++r)
            ctxs[w][16 * s + 4 * g + r][c] = (unsigned short)f2bf(accC[s][ct][r]);
        }
      }
  }

  float m0s = -3e38f, m1s = -3e38f, l0s = 0.f, l1s = 0.f;
  f32x4 accO[2][4];
#pragma unroll
  for (int s = 0; s < 2; ++s)
#pragma unroll
    for (int dt = 0; dt < 4; ++dt) accO[s][dt] = (f32x4){0.f, 0.f, 0.f, 0.f};

  const int swv = (ln & 7) << 3;

  for (int jt = 0; jt < 10; ++jt) {
    __syncthreads();  // B_a: previous compute's LDS reads (and Rp reads) done
    *(short8*)&Kt[tK]        = kr0;
    *(short8*)&Kt[2048 + tK] = kr1;
    *(short8*)&Vt[tK]        = vr0;
    *(short8*)&Vt[2048 + tK] = vr1;
    *(int4*)&rpbt[rpRow * 68 + rpCol]      = rp0_;
    *(int4*)&rpbt[rpRow * 68 + rpCol + 16] = rp1_;
    __syncthreads();  // B_b: tiles visible

    if (jt < 9) {  // prefetch next tile
      const int jn = jt * 64 + 64;
      kr0 = *(const short8*)(Kbh + (size_t)jn * 64 + tK);
      kr1 = *(const short8*)(Kbh + (size_t)jn * 64 + 2048 + tK);
      vr0 = *(const short8*)(Vbh + (size_t)vRow * SP_ + jn + vCol);
      vr1 = *(const short8*)(Vbh + (size_t)(32 + vRow) * SP_ + jn + vCol);
      rp0_ = *(const int4*)(rpbu8 + (size_t)irow_s * 640 + jn + rpCol);
      rp1_ = *(const int4*)(rpbu8 + (size_t)irow_s * 640 + jn + rpCol + 16);
    }

    // QK^T both sets (K frags shared): accS[s][nt][r] = S_s[i=ln][j=nt*16+4g+r]
    f32x4 accS[2][4];
#pragma unroll
    for (int s = 0; s < 2; ++s)
#pragma unroll
      for (int nt = 0; nt < 4; ++nt) accS[s][nt] = (f32x4){0.f, 0.f, 0.f, 0.f};
    __builtin_amdgcn_s_setprio(1);
#pragma unroll
    for (int kc = 0; kc < 2; ++kc) {
      const int cb = (kc * 32 + 8 * g) ^ swv;
#pragma unroll
      for (int nt = 0; nt < 4; ++nt) {
        const short8 kf = *(const short8*)&Kt[(nt * 16 + ln) * 64 + cb];
        accS[0][nt] = __builtin_amdgcn_mfma_f32_16x16x32_bf16(kf, qf[0][kc], accS[0][nt], 0, 0, 0);
        accS[1][nt] = __builtin_amdgcn_mfma_f32_16x16x32_bf16(kf, qf[1][kc], accS[1][nt], 0, 0, 0);
      }
    }
    __builtin_amdgcn_s_setprio(0);

    // per set: bias + softmax + pack
    short8 pf[2][2];
#pragma unroll
    for (int s = 0; s < 2; ++s) {
      const unsigned short* cbase = &ctxs[w][16 * s + ln][0];
      const int rpoff = (32 * w + 16 * s + ln) * 68;
      float pv[4][4];
#pragma unroll
      for (int nt = 0; nt < 4; ++nt) {
        const uchar4 bk = *(const uchar4*)&rpbt[rpoff + nt * 16 + 4 * g];
        pv[nt][0] = accS[s][nt][0] + bf2f(cbase[bk.x]);
        pv[nt][1] = accS[s][nt][1] + bf2f(cbase[bk.y]);
        pv[nt][2] = accS[s][nt][2] + bf2f(cbase[bk.z]);
        pv[nt][3] = accS[s][nt][3] + bf2f(cbase[bk.w]);
      }
      if (jt == 9) {  // tail: REPLACE invalid-j entries (poison-proof)
#pragma unroll
        for (int nt = 0; nt < 4; ++nt) {
          const int jb = jt * 64 + nt * 16 + 4 * g;
#pragma unroll
          for (int r = 0; r < 4; ++r)
            if (jb + r >= SN_) pv[nt][r] = -3e38f;
        }
      }

      float& m = (s == 0) ? m0s : m1s;
      float& l = (s == 0) ? l0s : l1s;

      float mq[4];
#pragma unroll
      for (int nt = 0; nt < 4; ++nt)
        mq[nt] = fmaxf(fmaxf(pv[nt][0], pv[nt][1]), fmaxf(pv[nt][2], pv[nt][3]));
      float mx = fmaxf(fmaxf(mq[0], mq[1]), fmaxf(mq[2], mq[3]));
      mx = fmaxf(mx, __shfl_xor(mx, 16));
      mx = fmaxf(mx, __shfl_xor(mx, 32));

      if (__any(mx > m + 8.f)) {
        const float mnew = fmaxf(m, mx);
        const float sc = ex2(m - mnew);
        float scr[4];
#pragma unroll
        for (int r = 0; r < 4; ++r) scr[r] = __shfl(sc, 4 * g + r);
#pragma unroll
        for (int dt = 0; dt < 4; ++dt)
#pragma unroll
          for (int r = 0; r < 4; ++r) accO[s][dt][r] *= scr[r];
        l *= sc;
        m = mnew;
      }

#pragma unroll
      for (int nt = 0; nt < 4; ++nt)
#pragma unroll
        for (int r = 0; r < 4; ++r)
          pv[nt][r] = ex2(pv[nt][r] - m);
      float sq[4];
#pragma unroll
      for (int nt = 0; nt < 4; ++nt)
        sq[nt] = (pv[nt][0] + pv[nt][1]) + (pv[nt][2] + pv[nt][3]);
      float sum = (sq[0] + sq[1]) + (sq[2] + sq[3]);
      sum += __shfl_xor(sum, 16);
      sum += __shfl_xor(sum, 32);
      l += sum;

#pragma unroll
      for (int kc = 0; kc < 2; ++kc) {
        union { short8 v; unsigned wd[4]; } pk;
        pk.wd[0] = cvtpk(pv[2 * kc][0],     pv[2 * kc][1]);
        pk.wd[1] = cvtpk(pv[2 * kc][2],     pv[2 * kc][3]);
        pk.wd[2] = cvtpk(pv[2 * kc + 1][0], pv[2 * kc + 1][1]);
        pk.wd[3] = cvtpk(pv[2 * kc + 1][2], pv[2 * kc + 1][3]);
        pf[s][kc] = pk.v;
      }
    }

    // PV both sets (V frags shared, single b128 each thanks to permuted V)
    __builtin_amdgcn_s_setprio(1);
#pragma unroll
    for (int kc = 0; kc < 2; ++kc) {
      const int cb = (kc * 32 + 8 * g) ^ swv;
#pragma unroll
      for (int dt = 0; dt < 4; ++dt) {
        const short8 vf = *(const short8*)&Vt[(dt * 16 + ln) * 64 + cb];
        accO[0][dt] = __builtin_amdgcn_mfma_f32_16x16x32_bf16(pf[0][kc], vf, accO[0][dt], 0, 0, 0);
        accO[1][dt] = __builtin_amdgcn_mfma_f32_16x16x32_bf16(pf[1][kc], vf, accO[1][dt], 0, 0, 0);
      }
    }
    __builtin_amdgcn_s_setprio(0);
  }

  // epilogue: y[b, i, h*64 + d] = O / l
#pragma unroll
  for (int s = 0; s < 2; ++s) {
    const float lv = (s == 0) ? l0s : l1s;
    float linv[4];
#pragma unroll
    for (int r = 0; r < 4; ++r) linv[r] = 1.f / __shfl(lv, 4 * g + r);
#pragma unroll
    for (int r = 0; r < 4; ++r) {
      const int i = i0 + 32 * w + 16 * s + 4 * g + r;
      if (i >= SN_) continue;
      float* yp = y + ((size_t)b * SN_ + i) * DN_ + h * HD_ + ln;
#pragma unroll
      for (int dt = 0; dt < 4; ++dt) yp[dt * 16] = accO[s][dt][r] * linv[r];
    }
  }
}

// ---------------------------------------------------------------------------
extern "C" void kernel_launch(void* const* d_in, const int* in_sizes, int n_in,
                              void* d_out, int out_size, void* d_ws, size_t ws_size,
                              hipStream_t stream) {
  const float* x   = (const float*)d_in[0];
  const float* w   = (const float*)d_in[1];
  const float* rpe = (const float*)d_in[2];
  const int*   rpb = (const int*)d_in[3];
  float* y = (float*)d_out;

  short* xb   = (short*)d_ws;                      // 9344*768
  short* wb   = xb + (size_t)MRP_ * DN_;           // 2304*768
  short* Qbf  = wb + (size_t)NQ_ * DN_;            // 110784*64
  short* Ksw  = Qbf + (size_t)BHS_ * HD_;          // 192*640*64
  short* Vbf  = Ksw + (size_t)BN_ * HN_ * SP_ * 64;
  short* Vtsw = Vbf + (size_t)BN_ * HN_ * SP_ * 64;
  unsigned char* rpbu8 = (unsigned char*)(Vtsw + (size_t)BN_ * HN_ * 64 * SP_);  // 577*640

  cvt_k<<<dim3(MRP_ * DN_ / 2048), 256, 0, stream>>>(x, xb, MR_ * DN_, MRP_ * DN_);
  cvt_k<<<dim3(NQ_ * DN_ / 2048), 256, 0, stream>>>(w, wb, NQ_ * DN_, NQ_ * DN_);
  rpb8_k<<<dim3((SN_ * 160 + 255) / 256), 256, 0, stream>>>(rpb, rpbu8);
  qkv_mfma_k<<<dim3(18, 73), 256, 0, stream>>>(xb, wb, Qbf, Ksw, Vbf);
  vtr_k<<<dim3(10, BN_ * HN_), 256, 0, stream>>>(Vbf, Vtsw);
  attn_k<<<dim3(960), 256, 0, stream>>>(Qbf, Ksw, Vtsw, rpe, rpbu8, y);
}

// Round 11
// 143.893 us; speedup vs baseline: 1.1297x; 1.0305x over previous
//
#include <hip/hip_runtime.h>

// Problem constants
constexpr int BN_  = 16;                 // batch
constexpr int SN_  = 577;                // seq
constexpr int SP_  = 640;                // padded seq (multiple of 64)
constexpr int DN_  = 768;                // model dim
constexpr int HN_  = 12;                 // heads
constexpr int HD_  = 64;                 // head dim
constexpr int NB_  = 50;                 // rpe buckets
constexpr int MR_  = BN_ * SN_;          // 9232 rows of x
constexpr int MRP_ = 73 * 128;           // 9344 padded rows
constexpr int NQ_  = 3 * DN_;            // 2304 qkv cols
constexpr int BHS_ = BN_ * HN_ * SN_;    // 110784 (b,h,i) rows
constexpr int SHD_ = SN_ * HD_;          // 36928

typedef __attribute__((ext_vector_type(8))) short short8;
typedef __attribute__((ext_vector_type(4))) float f32x4;

__device__ __forceinline__ short f2bf(float f) {
  union { float f; unsigned u; } v; v.f = f;
  unsigned r = (v.u + 0x7fffu + ((v.u >> 16) & 1u)) >> 16;
  return (short)r;
}

// raw v_exp_f32: D = 2^S0 (handles -3e38 -> 0)
__device__ __forceinline__ float ex2(float x) {
  float r; asm("v_exp_f32 %0, %1" : "=v"(r) : "v"(x)); return r;
}

// v_cvt_pk_bf16_f32: dst = {lo16=bf16(a), hi16=bf16(b)}
__device__ __forceinline__ unsigned cvtpk(float a, float b) {
  unsigned r; asm("v_cvt_pk_bf16_f32 %0, %1, %2" : "=v"(r) : "v"(a), "v"(b));
  return r;
}

__device__ __forceinline__ float bf2f(unsigned short u) {
  union { unsigned u; float f; } v; v.u = ((unsigned)u) << 16; return v.f;
}

// async global->LDS, 16B per lane; LDS dest is wave-uniform base + lane*16
__device__ __forceinline__ void gload16(const void* g, void* l) {
  __builtin_amdgcn_global_load_lds(
      (const __attribute__((address_space(1))) unsigned int*)g,
      (__attribute__((address_space(3))) unsigned int*)l, 16, 0, 0);
}

// ---------------------------------------------------------------------------
// Kernel 0: f32 -> bf16 convert (pads dst beyond n_src with zeros)
// ---------------------------------------------------------------------------
__launch_bounds__(256)
__global__ void cvt_k(const float* __restrict__ src, short* __restrict__ dst,
                      int n_src, int n_dst) {
  const int i = (blockIdx.x * 256 + threadIdx.x) * 8;
  if (i >= n_dst) return;
  union { short8 v; short u[8]; } pk;
  if (i < n_src) {
    const float4 a = *(const float4*)(src + i);
    const float4 b = *(const float4*)(src + i + 4);
    pk.u[0] = f2bf(a.x); pk.u[1] = f2bf(a.y); pk.u[2] = f2bf(a.z); pk.u[3] = f2bf(a.w);
    pk.u[4] = f2bf(b.x); pk.u[5] = f2bf(b.y); pk.u[6] = f2bf(b.z); pk.u[7] = f2bf(b.w);
  } else {
#pragma unroll
    for (int j = 0; j < 8; ++j) pk.u[j] = 0;
  }
  *(short8*)(dst + i) = pk.v;
}

// ---------------------------------------------------------------------------
// Kernel 0b: rp_bucket int32 [577][577] -> u8 [577][640] (pad j with 0)
// ---------------------------------------------------------------------------
__launch_bounds__(256)
__global__ void rpb8_k(const int* __restrict__ rpb, unsigned char* __restrict__ rpbu8) {
  const int tid = blockIdx.x * 256 + threadIdx.x;
  if (tid >= SN_ * 160) return;
  const int i = tid / 160, c4 = tid - i * 160;
  const int j = c4 * 4;
  uchar4 o;
  o.x = (j     < SN_) ? (unsigned char)rpb[i * SN_ + j    ] : 0;
  o.y = (j + 1 < SN_) ? (unsigned char)rpb[i * SN_ + j + 1] : 0;
  o.z = (j + 2 < SN_) ? (unsigned char)rpb[i * SN_ + j + 2] : 0;
  o.w = (j + 3 < SN_) ? (unsigned char)rpb[i * SN_ + j + 3] : 0;
  *(uchar4*)(rpbu8 + (size_t)i * 640 + j) = o;
}

// ---------------------------------------------------------------------------
// Kernel 1: qkv = x @ w^T in bf16 MFMA. 128x128 tile, BK=64, 4 waves (2x2).
// DOUBLE-BUFFERED global_load_lds: loads for tile k+1 issued into buf^1
// right after the barrier, full compute phase to land, ONE barrier/K-step.
// Per-lane global source pre-swizzled -> linear LDS dest reproduces the XOR
// layout LDS[row][u] = G[row][u^(row&7)].
// Epilogue: stage C (bf16) through LDS (stride 72), one div-chain + 8
// coalesced 16B stores per row.
// ---------------------------------------------------------------------------
__launch_bounds__(256)
__global__ void qkv_mfma_k(const short* __restrict__ xb, const short* __restrict__ wb,
                           short* __restrict__ Qbf, short* __restrict__ Ksw,
                           short* __restrict__ Vbf) {
  __shared__ short SB[32768];   // 64 KB: A buf0|A buf1|B buf0|B buf1; epilogue reuse
  const int t = threadIdx.x;
  const int w = t >> 6, lane = t & 63, g = lane >> 4, ln = lane & 15;
  const int wm = w >> 1, wn = w & 1;
  const int m0 = blockIdx.y * 128, n0 = blockIdx.x * 128;

  // gload16 maps: wave w, chunk q (0..3) covers rows w*32+q*8 .. +8.
  // lane l -> row_local = base + (l>>3), global unit gu = (l&7)^(l>>3).
  const int rlo = lane >> 3;
  const int gu  = (lane & 7) ^ rlo;
  const short* ga[4]; const short* gb[4];
  int lOff[4];
#pragma unroll
  for (int q = 0; q < 4; ++q) {
    const int rl = w * 32 + q * 8 + rlo;
    ga[q] = xb + (size_t)(m0 + rl) * DN_ + gu * 8;
    gb[q] = wb + (size_t)(n0 + rl) * DN_ + gu * 8;
    lOff[q] = w * 2048 + q * 512;     // wave-uniform (shorts)
  }

  f32x4 acc[4][4];
#pragma unroll
  for (int mt = 0; mt < 4; ++mt)
#pragma unroll
    for (int nt = 0; nt < 4; ++nt) acc[mt][nt] = (f32x4){0.f, 0.f, 0.f, 0.f};

  // prologue: tile 0 -> buf 0
#pragma unroll
  for (int q = 0; q < 4; ++q) {
    gload16(ga[q], SB + lOff[q]);                // A buf0 at 0
    gload16(gb[q], SB + 16384 + lOff[q]);        // B buf0 at 16384
  }
  __syncthreads();

  int cur = 0;
  for (int k0 = 0; k0 < DN_; k0 += 64) {
    if (k0 + 64 < DN_) {  // issue next tile into the other buffer (async)
      const int nb = (cur ^ 1) * 8192;
#pragma unroll
      for (int q = 0; q < 4; ++q) {
        gload16(ga[q] + k0 + 64, SB + nb + lOff[q]);
        gload16(gb[q] + k0 + 64, SB + 16384 + nb + lOff[q]);
      }
    }
    const short* Ac = SB + cur * 8192;
    const short* Bc = SB + 16384 + cur * 8192;
#pragma unroll
    for (int kc = 0; kc < 2; ++kc) {
      short8 af[4], bf[4];
#pragma unroll
      for (int mt = 0; mt < 4; ++mt) {
        const int row = wm * 64 + mt * 16 + ln;
        const int u = (kc * 4 + g) ^ (row & 7);
        af[mt] = *(const short8*)&Ac[row * 64 + u * 8];
      }
#pragma unroll
      for (int nt = 0; nt < 4; ++nt) {
        const int row = wn * 64 + nt * 16 + ln;
        const int u = (kc * 4 + g) ^ (row & 7);
        bf[nt] = *(const short8*)&Bc[row * 64 + u * 8];
      }
#pragma unroll
      for (int mt = 0; mt < 4; ++mt)
#pragma unroll
        for (int nt = 0; nt < 4; ++nt)
          acc[mt][nt] = __builtin_amdgcn_mfma_f32_16x16x32_bf16(af[mt], bf[nt], acc[mt][nt], 0, 0, 0);
    }
    __syncthreads();  // drains vmcnt (next tile landed) + all reads of cur done
    cur ^= 1;
  }

  // ---- epilogue: stage C tile (bf16) through LDS, coalesced 16B stores ----
  const int wbase = w * 4608;               // 64 rows x stride 72 per wave
  const int nw0  = n0 + wn * 64;
  const int secg = nw0 / DN_;               // uniform per wave
  const int cbw  = nw0 - secg * DN_;
  const float QSC = 0.18033688011112042f;   // log2(e) / 8
#pragma unroll
  for (int mt = 0; mt < 4; ++mt)
#pragma unroll
    for (int nt = 0; nt < 4; ++nt)
#pragma unroll
      for (int r = 0; r < 4; ++r) {
        float v = acc[mt][nt][r];
        if (secg == 0) v *= QSC;
        SB[wbase + (mt * 16 + 4 * g + r) * 72 + nt * 16 + ln] = f2bf(v);
      }
  // same-wave RAW through own LDS region; no barrier needed
  const int gm = m0 + wm * 64 + lane;
  if (gm < MR_) {
    const int bb = gm / SN_;
    const int ss = gm - bb * SN_;
    const int pr = ss * DN_ + cbw;          // multiple of 64
    const int hh = pr / SHD_;
    const int ii = (pr - hh * SHD_) >> 6;   // rem is 64-aligned -> dd0 = 0
    const size_t ro = (size_t)(bb * HN_ + hh);
    const short* src = SB + wbase + lane * 72;
    if (secg == 0) {
      short* dst = Qbf + (ro * SN_ + ii) * 64;
#pragma unroll
      for (int u = 0; u < 8; ++u)
        *(short8*)(dst + u * 8) = *(const short8*)(src + u * 8);
    } else if (secg == 1) {
      short* dst = Ksw + (ro * SP_ + ii) * 64;
      const int sw = ii & 7;
#pragma unroll
      for (int u = 0; u < 8; ++u)
        *(short8*)(dst + (u ^ sw) * 8) = *(const short8*)(src + u * 8);
    } else {
      short* dst = Vbf + (ro * SP_ + ii) * 64;
#pragma unroll
      for (int u = 0; u < 8; ++u)
        *(short8*)(dst + u * 8) = *(const short8*)(src + u * 8);
    }
  }
}

// ---------------------------------------------------------------------------
// Kernel 2: transpose V per (bh): Vbf[j][d] -> Vtsw[d][pi(j)], bf16.
// pi permutes quads within each 32-col block: oq -> 2*(oq&3) + (oq>>2),
// so the attention PV custom slot map reads ONE contiguous b128 per frag.
// Then XOR-swizzle on 8-short units with (d&7). Pad cols j>=577 zeroed.
// ---------------------------------------------------------------------------
__launch_bounds__(256)
__global__ void vtr_k(const short* __restrict__ Vbf, short* __restrict__ Vtsw) {
  __shared__ short T[64][72];
  const int t = threadIdx.x;
  const int jt = blockIdx.x, bh = blockIdx.y;
  const int j0 = jt * 64;
  {
    const int r = t >> 2, c0 = (t & 3) * 16;
    const short* src = Vbf + ((size_t)bh * SP_ + j0 + r) * 64 + c0;
    *(short8*)&T[r][c0]     = *(const short8*)(src);
    *(short8*)&T[r][c0 + 8] = *(const short8*)(src + 8);
  }
  __syncthreads();
  const int d = t >> 2;
  short* dst = Vtsw + ((size_t)bh * 64 + d) * SP_;
  const int sw = (d & 7) << 3;
#pragma unroll
  for (int e = 0; e < 4; ++e) {
    const int jl = (t & 3) * 16 + e * 4;
    const int jg = j0 + jl;
    short4 v;
    v.x = (jg + 0 < SN_) ? T[jl + 0][d] : (short)0;
    v.y = (jg + 1 < SN_) ? T[jl + 1][d] : (short)0;
    v.z = (jg + 2 < SN_) ? T[jl + 2][d] : (short)0;
    v.w = (jg + 3 < SN_) ? T[jl + 3][d] : (short)0;
    const int oq = (jg >> 2) & 7;
    const int pq = ((oq & 3) << 1) | (oq >> 2);
    const int p  = (jg & ~31) | (pq << 2);
    *(short4*)&dst[p ^ sw] = v;
  }
}

// ---------------------------------------------------------------------------
// Kernel 3: MFMA flash attention (unchanged from R8/R9). q-tile 128: 4 waves
// x 32 q-rows (2 sets of 16). K/V frags shared by both sets; permuted V ->
// single-b128 PV frags. Swapped-QK in-reg softmax, exp2, u8 buckets, bf16
// ctx, cvtpk pack, setprio, defer-max, XCD swizzle.
// ---------------------------------------------------------------------------
__launch_bounds__(256)
__global__ void attn_k(const short* __restrict__ Qbf, const short* __restrict__ Ksw,
                       const short* __restrict__ Vtsw, const float* __restrict__ rpe,
                       const unsigned char* __restrict__ rpbu8, float* __restrict__ y) {
  __shared__ short Kt[4096];                  // 8 KB
  __shared__ short Vt[4096];                  // 8 KB
  __shared__ unsigned char rpbt[128 * 68];    // 8.5 KB; unioned with Rp (8 KB)
  __shared__ unsigned short ctxs[4][32][53];  // 13.25 KB bf16
  short (*Rp)[64] = (short (*)[64])rpbt;

  const int t = threadIdx.x;
  const int w = t >> 6, lane = t & 63, g = lane >> 4, ln = lane & 15;
  // XCD swizzle: all 5 q-tiles of one bh share an XCD
  const int wg = blockIdx.x;
  const int xcd = wg & 7, idx = wg >> 3;
  const int qt = idx % 5;
  const int bh = (idx / 5) * 8 + xcd;
  const int b = bh / HN_, h = bh - b * HN_;
  const int i0 = qt * 128;
  const size_t rb = (size_t)bh * SN_;
  const short* Kbh = Ksw + (size_t)bh * SP_ * 64;
  const short* Vbh = Vtsw + (size_t)bh * 64 * SP_;

  // staging maps
  const int tK = t * 8;                          // K/V: linear, 2x 16B
  const int vRow = t >> 3, vCol = (t & 7) * 8;   // V global rows
  const int rpRow = t >> 1, rpCol = (t & 1) * 32;  // rpb: 128 rows x 32B
  const int irow_s = (i0 + rpRow <= SN_ - 1) ? (i0 + rpRow) : (SN_ - 1);

  // issue tile 0 loads
  short8 kr0, kr1, vr0, vr1; int4 rp0_, rp1_;
  kr0 = *(const short8*)(Kbh + tK);
  kr1 = *(const short8*)(Kbh + 2048 + tK);
  vr0 = *(const short8*)(Vbh + (size_t)vRow * SP_ + vCol);
  vr1 = *(const short8*)(Vbh + (size_t)(32 + vRow) * SP_ + vCol);
  rp0_ = *(const int4*)(rpbu8 + (size_t)irow_s * 640 + rpCol);
  rp1_ = *(const int4*)(rpbu8 + (size_t)irow_s * 640 + rpCol + 16);

  // stage rpe^T -> Rp[c][d] (bf16), pad c>=50 with 0
  for (int e = t; e < 64 * 64; e += 256) {
    const int c = e >> 6, d = e & 63;
    Rp[c][d] = (c < NB_) ? f2bf(rpe[d * NB_ + c]) : (short)0;
  }

  // Q fragments, 2 sets: set s covers rows i0 + 32w + 16s + ln
  short8 qf[2][2];
#pragma unroll
  for (int s = 0; s < 2; ++s) {
    int row = i0 + 32 * w + 16 * s + ln; if (row > SN_ - 1) row = SN_ - 1;
    const short* qp = Qbf + (rb + row) * 64;
    qf[s][0] = *(const short8*)(qp + 8 * g);
    qf[s][1] = *(const short8*)(qp + 32 + 8 * g);
  }

  __syncthreads();  // B1: Rp visible

  // ctx tiles (both sets): ctx[32w+16s+4g+r][c=ct*16+ln]
  {
    f32x4 accC[2][4];
#pragma unroll
    for (int s = 0; s < 2; ++s)
#pragma unroll
      for (int ct = 0; ct < 4; ++ct) accC[s][ct] = (f32x4){0.f, 0.f, 0.f, 0.f};
#pragma unroll
    for (int kc = 0; kc < 2; ++kc) {
#pragma unroll
      for (int ct = 0; ct < 4; ++ct) {
        const short8 rf = *(const short8*)&Rp[ct * 16 + ln][kc * 32 + 8 * g];
        accC[0][ct] = __builtin_amdgcn_mfma_f32_16x16x32_bf16(qf[0][kc], rf, accC[0][ct], 0, 0, 0);
        accC[1][ct] = __builtin_amdgcn_mfma_f32_16x16x32_bf16(qf[1][kc], rf, accC[1][ct], 0, 0, 0);
      }
    }
#pragma unroll
    for (int s = 0; s < 2; ++s)
#pragma unroll
      for (int ct = 0; ct < 4; ++ct) {
        const int c = ct * 16 + ln;
        if (c < 53) {
#pragma unroll
          for (int r = 0; r < 4; ++r)
            ctxs[w][16 * s + 4 * g + r][c] = (unsigned short)f2bf(accC[s][ct][r]);
        }
      }
  }

  float m0s = -3e38f, m1s = -3e38f, l0s = 0.f, l1s = 0.f;
  f32x4 accO[2][4];
#pragma unroll
  for (int s = 0; s < 2; ++s)
#pragma unroll
    for (int dt = 0; dt < 4; ++dt) accO[s][dt] = (f32x4){0.f, 0.f, 0.f, 0.f};

  const int swv = (ln & 7) << 3;

  for (int jt = 0; jt < 10; ++jt) {
    __syncthreads();  // B_a: previous compute's LDS reads (and Rp reads) done
    *(short8*)&Kt[tK]        = kr0;
    *(short8*)&Kt[2048 + tK] = kr1;
    *(short8*)&Vt[tK]        = vr0;
    *(short8*)&Vt[2048 + tK] = vr1;
    *(int4*)&rpbt[rpRow * 68 + rpCol]      = rp0_;
    *(int4*)&rpbt[rpRow * 68 + rpCol + 16] = rp1_;
    __syncthreads();  // B_b: tiles visible

    if (jt < 9) {  // prefetch next tile
      const int jn = jt * 64 + 64;
      kr0 = *(const short8*)(Kbh + (size_t)jn * 64 + tK);
      kr1 = *(const short8*)(Kbh + (size_t)jn * 64 + 2048 + tK);
      vr0 = *(const short8*)(Vbh + (size_t)vRow * SP_ + jn + vCol);
      vr1 = *(const short8*)(Vbh + (size_t)(32 + vRow) * SP_ + jn + vCol);
      rp0_ = *(const int4*)(rpbu8 + (size_t)irow_s * 640 + jn + rpCol);
      rp1_ = *(const int4*)(rpbu8 + (size_t)irow_s * 640 + jn + rpCol + 16);
    }

    // QK^T both sets (K frags shared): accS[s][nt][r] = S_s[i=ln][j=nt*16+4g+r]
    f32x4 accS[2][4];
#pragma unroll
    for (int s = 0; s < 2; ++s)
#pragma unroll
      for (int nt = 0; nt < 4; ++nt) accS[s][nt] = (f32x4){0.f, 0.f, 0.f, 0.f};
    __builtin_amdgcn_s_setprio(1);
#pragma unroll
    for (int kc = 0; kc < 2; ++kc) {
      const int cb = (kc * 32 + 8 * g) ^ swv;
#pragma unroll
      for (int nt = 0; nt < 4; ++nt) {
        const short8 kf = *(const short8*)&Kt[(nt * 16 + ln) * 64 + cb];
        accS[0][nt] = __builtin_amdgcn_mfma_f32_16x16x32_bf16(kf, qf[0][kc], accS[0][nt], 0, 0, 0);
        accS[1][nt] = __builtin_amdgcn_mfma_f32_16x16x32_bf16(kf, qf[1][kc], accS[1][nt], 0, 0, 0);
      }
    }
    __builtin_amdgcn_s_setprio(0);

    // per set: bias + softmax + pack
    short8 pf[2][2];
#pragma unroll
    for (int s = 0; s < 2; ++s) {
      const unsigned short* cbase = &ctxs[w][16 * s + ln][0];
      const int rpoff = (32 * w + 16 * s + ln) * 68;
      float pv[4][4];
#pragma unroll
      for (int nt = 0; nt < 4; ++nt) {
        const uchar4 bk = *(const uchar4*)&rpbt[rpoff + nt * 16 + 4 * g];
        pv[nt][0] = accS[s][nt][0] + bf2f(cbase[bk.x]);
        pv[nt][1] = accS[s][nt][1] + bf2f(cbase[bk.y]);
        pv[nt][2] = accS[s][nt][2] + bf2f(cbase[bk.z]);
        pv[nt][3] = accS[s][nt][3] + bf2f(cbase[bk.w]);
      }
      if (jt == 9) {  // tail: REPLACE invalid-j entries (poison-proof)
#pragma unroll
        for (int nt = 0; nt < 4; ++nt) {
          const int jb = jt * 64 + nt * 16 + 4 * g;
#pragma unroll
          for (int r = 0; r < 4; ++r)
            if (jb + r >= SN_) pv[nt][r] = -3e38f;
        }
      }

      float& m = (s == 0) ? m0s : m1s;
      float& l = (s == 0) ? l0s : l1s;

      float mq[4];
#pragma unroll
      for (int nt = 0; nt < 4; ++nt)
        mq[nt] = fmaxf(fmaxf(pv[nt][0], pv[nt][1]), fmaxf(pv[nt][2], pv[nt][3]));
      float mx = fmaxf(fmaxf(mq[0], mq[1]), fmaxf(mq[2], mq[3]));
      mx = fmaxf(mx, __shfl_xor(mx, 16));
      mx = fmaxf(mx, __shfl_xor(mx, 32));

      if (__any(mx > m + 8.f)) {
        const float mnew = fmaxf(m, mx);
        const float sc = ex2(m - mnew);
        float scr[4];
#pragma unroll
        for (int r = 0; r < 4; ++r) scr[r] = __shfl(sc, 4 * g + r);
#pragma unroll
        for (int dt = 0; dt < 4; ++dt)
#pragma unroll
          for (int r = 0; r < 4; ++r) accO[s][dt][r] *= scr[r];
        l *= sc;
        m = mnew;
      }

#pragma unroll
      for (int nt = 0; nt < 4; ++nt)
#pragma unroll
        for (int r = 0; r < 4; ++r)
          pv[nt][r] = ex2(pv[nt][r] - m);
      float sq[4];
#pragma unroll
      for (int nt = 0; nt < 4; ++nt)
        sq[nt] = (pv[nt][0] + pv[nt][1]) + (pv[nt][2] + pv[nt][3]);
      float sum = (sq[0] + sq[1]) + (sq[2] + sq[3]);
      sum += __shfl_xor(sum, 16);
      sum += __shfl_xor(sum, 32);
      l += sum;

#pragma unroll
      for (int kc = 0; kc < 2; ++kc) {
        union { short8 v; unsigned wd[4]; } pk;
        pk.wd[0] = cvtpk(pv[2 * kc][0],     pv[2 * kc][1]);
        pk.wd[1] = cvtpk(pv[2 * kc][2],     pv[2 * kc][3]);
        pk.wd[2] = cvtpk(pv[2 * kc + 1][0], pv[2 * kc + 1][1]);
        pk.wd[3] = cvtpk(pv[2 * kc + 1][2], pv[2 * kc + 1][3]);
        pf[s][kc] = pk.v;
      }
    }

    // PV both sets (V frags shared, single b128 each thanks to permuted V)
    __builtin_amdgcn_s_setprio(1);
#pragma unroll
    for (int kc = 0; kc < 2; ++kc) {
      const int cb = (kc * 32 + 8 * g) ^ swv;
#pragma unroll
      for (int dt = 0; dt < 4; ++dt) {
        const short8 vf = *(const short8*)&Vt[(dt * 16 + ln) * 64 + cb];
        accO[0][dt] = __builtin_amdgcn_mfma_f32_16x16x32_bf16(pf[0][kc], vf, accO[0][dt], 0, 0, 0);
        accO[1][dt] = __builtin_amdgcn_mfma_f32_16x16x32_bf16(pf[1][kc], vf, accO[1][dt], 0, 0, 0);
      }
    }
    __builtin_amdgcn_s_setprio(0);
  }

  // epilogue: y[b, i, h*64 + d] = O / l
#pragma unroll
  for (int s = 0; s < 2; ++s) {
    const float lv = (s == 0) ? l0s : l1s;
    float linv[4];
#pragma unroll
    for (int r = 0; r < 4; ++r) linv[r] = 1.f / __shfl(lv, 4 * g + r);
#pragma unroll
    for (int r = 0; r < 4; ++r) {
      const int i = i0 + 32 * w + 16 * s + 4 * g + r;
      if (i >= SN_) continue;
      float* yp = y + ((size_t)b * SN_ + i) * DN_ + h * HD_ + ln;
#pragma unroll
      for (int dt = 0; dt < 4; ++dt) yp[dt * 16] = accO[s][dt][r] * linv[r];
    }
  }
}

// ---------------------------------------------------------------------------
extern "C" void kernel_launch(void* const* d_in, const int* in_sizes, int n_in,
                              void* d_out, int out_size, void* d_ws, size_t ws_size,
                              hipStream_t stream) {
  const float* x   = (const float*)d_in[0];
  const float* w   = (const float*)d_in[1];
  const float* rpe = (const float*)d_in[2];
  const int*   rpb = (const int*)d_in[3];
  float* y = (float*)d_out;

  short* xb   = (short*)d_ws;                      // 9344*768
  short* wb   = xb + (size_t)MRP_ * DN_;           // 2304*768
  short* Qbf  = wb + (size_t)NQ_ * DN_;            // 110784*64
  short* Ksw  = Qbf + (size_t)BHS_ * HD_;          // 192*640*64
  short* Vbf  = Ksw + (size_t)BN_ * HN_ * SP_ * 64;
  short* Vtsw = Vbf + (size_t)BN_ * HN_ * SP_ * 64;
  unsigned char* rpbu8 = (unsigned char*)(Vtsw + (size_t)BN_ * HN_ * 64 * SP_);  // 577*640

  cvt_k<<<dim3(MRP_ * DN_ / 2048), 256, 0, stream>>>(x, xb, MR_ * DN_, MRP_ * DN_);
  cvt_k<<<dim3(NQ_ * DN_ / 2048), 256, 0, stream>>>(w, wb, NQ_ * DN_, NQ_ * DN_);
  rpb8_k<<<dim3((SN_ * 160 + 255) / 256), 256, 0, stream>>>(rpb, rpbu8);
  qkv_mfma_k<<<dim3(18, 73), 256, 0, stream>>>(xb, wb, Qbf, Ksw, Vbf);
  vtr_k<<<dim3(10, BN_ * HN_), 256, 0, stream>>>(Vbf, Vtsw);
  attn_k<<<dim3(960), 256, 0, stream>>>(Qbf, Ksw, Vtsw, rpe, rpbu8, y);
}